// Round 1
// baseline (1035.100 us; speedup 1.0000x reference)
//
#include <hip/hip_runtime.h>
#include <math.h>

#define Bn 64
#define Tn 2048
#define NCLS 20
#define Dn 2048
#define LCSL 64
#define FSDL 32

// ws float offsets
#define WS_ACC 0      // 4 floats: guide0, sparse0, guide1, sparse1 (atomic accumulators)
#define WS_PAIR 4     // 64
#define WS_LCS 68     // 64
#define WS_FSD 132    // 64
#define WS_NORM 196   // 6*64 = 384

// ---------------- pair label ----------------
__global__ void pair_kernel(const float* __restrict__ vid0, const float* __restrict__ vid1,
                            float* __restrict__ pl) {
    int b = threadIdx.x;
    if (b < Bn) {
        float s = 0.f;
        for (int c = 0; c < NCLS; ++c) s += vid0[b * NCLS + c] * vid1[b * NCLS + c];
        pl[b] = (s > 0.f) ? 1.f : 0.f;
    }
}

// ---------------- guide + sparse reduction ----------------
__global__ __launch_bounds__(256) void guide_sparse_kernel(
    const float* __restrict__ cas0, const float* __restrict__ att0,
    const float* __restrict__ cas1, const float* __restrict__ att1,
    float* __restrict__ acc) {
    const int N = Bn * Tn;
    float g0 = 0.f, s0 = 0.f, g1 = 0.f, s1 = 0.f;
    for (int n = blockIdx.x * blockDim.x + threadIdx.x; n < 2 * N;
         n += gridDim.x * blockDim.x) {
        int sfx = (n >= N);
        int m = sfx ? (n - N) : n;
        const float* cas = sfx ? cas1 : cas0;
        const float* att = sfx ? att1 : att0;
        float a0 = att[m * 3 + 0];
        float a1 = att[m * 3 + 1];
        float g = fabsf(1.0f - cas[m * (NCLS + 1) + NCLS] - a0);
        float s = a0 + a1;
        if (sfx) { g1 += g; s1 += s; } else { g0 += g; s0 += s; }
    }
    __shared__ float red[256];
    float vals[4] = {g0, s0, g1, s1};
    for (int v = 0; v < 4; ++v) {
        red[threadIdx.x] = vals[v];
        __syncthreads();
        for (int o = 128; o; o >>= 1) {
            if ((int)threadIdx.x < o) red[threadIdx.x] += red[threadIdx.x + o];
            __syncthreads();
        }
        if (threadIdx.x == 0) atomicAdd(&acc[v], red[0]);
        __syncthreads();
    }
}

// ---------------- feature norms ----------------
__global__ __launch_bounds__(256) void featnorm_kernel(
    const float* __restrict__ f0, const float* __restrict__ f1, const float* __restrict__ f2,
    const float* __restrict__ f3, const float* __restrict__ f4, const float* __restrict__ f5,
    float* __restrict__ norms) {
    int f = blockIdx.x / Bn;
    int row = blockIdx.x % Bn;
    const float* arr[6] = {f0, f1, f2, f3, f4, f5};
    const float* p = arr[f] + (size_t)row * Dn;
    float s = 0.f;
    for (int k = threadIdx.x; k < Dn; k += 256) { float v = p[k]; s += v * v; }
    __shared__ float red[256];
    red[threadIdx.x] = s;
    __syncthreads();
    for (int o = 128; o; o >>= 1) {
        if ((int)threadIdx.x < o) red[threadIdx.x] += red[threadIdx.x + o];
        __syncthreads();
    }
    if (threadIdx.x == 0) norms[f * Bn + row] = sqrtf(red[0]);
}

// ---------------- LCS: cos-sim GEMM + DP ----------------
__global__ __launch_bounds__(256) void lcs_kernel(const float* __restrict__ cand0,
                                                  const float* __restrict__ cand1,
                                                  float* __restrict__ lcs_out) {
    const int b = blockIdx.x;
    const float* c0 = cand0 + (size_t)b * LCSL * Dn;
    const float* c1 = cand1 + (size_t)b * LCSL * Dn;

    __shared__ float tileA[64 * 68];   // [k][row], padded to 68
    __shared__ float tileB[64 * 68];
    __shared__ float Smat[64][65];
    __shared__ float invn[128];

    const int t = threadIdx.x;
    const int w = t >> 6, lane = t & 63;

    // ---- row inverse norms (128 rows: 0..63 -> c0, 64..127 -> c1) ----
    for (int rr = 0; rr < 32; ++rr) {
        int r = w * 32 + rr;
        const float* p = (r < 64) ? (c0 + (size_t)r * Dn) : (c1 + (size_t)(r - 64) * Dn);
        float s = 0.f;
        for (int k = lane; k < Dn; k += 64) { float v = p[k]; s += v * v; }
        for (int off = 32; off; off >>= 1) s += __shfl_down(s, off);
        if (lane == 0) invn[r] = 1.0f / sqrtf(s);
    }
    __syncthreads();

    // ---- 64x64x2048 GEMM, 4x4 per thread ----
    const int ti = t >> 4, tj = t & 15;
    const int i0 = ti * 4, j0 = tj * 4;
    float acc[4][4] = {};
    for (int kc = 0; kc < Dn; kc += 64) {
        #pragma unroll
        for (int l = 0; l < 4; ++l) {
            int idx4 = l * 256 + t;          // 0..1023 float4 slots
            int row = idx4 >> 4;             // 16 float4 per row
            int kq = (idx4 & 15) * 4;
            float4 av = *(const float4*)(c0 + (size_t)row * Dn + kc + kq);
            float4 bv = *(const float4*)(c1 + (size_t)row * Dn + kc + kq);
            tileA[(kq + 0) * 68 + row] = av.x;
            tileA[(kq + 1) * 68 + row] = av.y;
            tileA[(kq + 2) * 68 + row] = av.z;
            tileA[(kq + 3) * 68 + row] = av.w;
            tileB[(kq + 0) * 68 + row] = bv.x;
            tileB[(kq + 1) * 68 + row] = bv.y;
            tileB[(kq + 2) * 68 + row] = bv.z;
            tileB[(kq + 3) * 68 + row] = bv.w;
        }
        __syncthreads();
        #pragma unroll 8
        for (int k = 0; k < 64; ++k) {
            float4 av = *(const float4*)&tileA[k * 68 + i0];
            float4 bv = *(const float4*)&tileB[k * 68 + j0];
            float a[4] = {av.x, av.y, av.z, av.w};
            float bb[4] = {bv.x, bv.y, bv.z, bv.w};
            #pragma unroll
            for (int r = 0; r < 4; ++r)
                #pragma unroll
                for (int c = 0; c < 4; ++c)
                    acc[r][c] = fmaf(a[r], bb[c], acc[r][c]);
        }
        __syncthreads();
    }
    #pragma unroll
    for (int r = 0; r < 4; ++r)
        #pragma unroll
        for (int c = 0; c < 4; ++c)
            Smat[i0 + r][j0 + c] = acc[r][c] * invn[i0 + r] * invn[64 + j0 + c];
    __syncthreads();

    // ---- LCS DP, anti-diagonal wavefront; reuse tileA as dp (65x66) ----
    float* dp = tileA;
    for (int i = t; i < 65 * 66; i += 256) dp[i] = 0.f;
    __syncthreads();
    for (int d = 2; d <= 128; ++d) {
        int i = t + 1;
        int j = d - i;
        if (t < 64 && j >= 1 && j <= 64) {
            float s = Smat[i - 1][j - 1];
            float val = (s > 0.5f)
                            ? (dp[(i - 1) * 66 + (j - 1)] + s)
                            : fmaxf(dp[(i - 1) * 66 + j], dp[i * 66 + (j - 1)]);
            dp[i * 66 + j] = val;
        }
        __syncthreads();
    }
    if (t == 0) lcs_out[b] = dp[64 * 66 + 64];
}

// ---------------- FSD: two cos-sim GEMMs + soft DP ----------------
__global__ __launch_bounds__(256) void fsd_kernel(const float* __restrict__ act0,
                                                  const float* __restrict__ act1,
                                                  const float* __restrict__ bak1,
                                                  const float* __restrict__ pair,
                                                  float* __restrict__ fsd_out) {
    const int b = blockIdx.x;
    const float* c0 = act0 + (size_t)b * FSDL * Dn;
    const float* c1 = ((pair[b] > 0.f) ? act1 : bak1) + (size_t)b * FSDL * Dn;

    __shared__ float tileA[64 * 36];   // [k][row] pad 36
    __shared__ float tileB[64 * 36];
    __shared__ float Mmat[32][33];
    __shared__ float Gmat[32][33];
    __shared__ float dpb[33 * 34];
    __shared__ float invn[128];  // [c0 h0, c0 h1, c1 h0, c1 h1] x 32 rows

    const int t = threadIdx.x;
    const int w = t >> 6, lane = t & 63;
    const int h = Dn / 2;  // 1024

    for (int rr = 0; rr < 32; ++rr) {
        int q = w * 32 + rr;
        int row = q & 31;
        int half = (q >> 5) & 1;
        const float* base = (q < 64) ? c0 : c1;
        const float* p = base + (size_t)row * Dn + half * h;
        float s = 0.f;
        for (int k = lane; k < h; k += 64) { float v = p[k]; s += v * v; }
        for (int off = 32; off; off >>= 1) s += __shfl_down(s, off);
        if (lane == 0) invn[q] = 1.0f / sqrtf(s);
    }
    __syncthreads();

    const int ti = t >> 4, tj = t & 15;
    const int i0 = ti * 2, j0 = tj * 2;
    for (int half = 0; half < 2; ++half) {
        float acc[2][2] = {};
        for (int kc = 0; kc < h; kc += 64) {
            #pragma unroll
            for (int l = 0; l < 2; ++l) {
                int idx4 = l * 256 + t;        // 0..511 float4 slots (32 rows x 16)
                int row = idx4 >> 4;
                int kq = (idx4 & 15) * 4;
                float4 av = *(const float4*)(c0 + (size_t)row * Dn + half * h + kc + kq);
                float4 bv = *(const float4*)(c1 + (size_t)row * Dn + half * h + kc + kq);
                tileA[(kq + 0) * 36 + row] = av.x;
                tileA[(kq + 1) * 36 + row] = av.y;
                tileA[(kq + 2) * 36 + row] = av.z;
                tileA[(kq + 3) * 36 + row] = av.w;
                tileB[(kq + 0) * 36 + row] = bv.x;
                tileB[(kq + 1) * 36 + row] = bv.y;
                tileB[(kq + 2) * 36 + row] = bv.z;
                tileB[(kq + 3) * 36 + row] = bv.w;
            }
            __syncthreads();
            #pragma unroll 8
            for (int k = 0; k < 64; ++k) {
                float2 av = *(const float2*)&tileA[k * 36 + i0];
                float2 bv = *(const float2*)&tileB[k * 36 + j0];
                acc[0][0] = fmaf(av.x, bv.x, acc[0][0]);
                acc[0][1] = fmaf(av.x, bv.y, acc[0][1]);
                acc[1][0] = fmaf(av.y, bv.x, acc[1][0]);
                acc[1][1] = fmaf(av.y, bv.y, acc[1][1]);
            }
            __syncthreads();
        }
        #pragma unroll
        for (int r = 0; r < 2; ++r)
            #pragma unroll
            for (int c = 0; c < 2; ++c) {
                float v = acc[r][c] * invn[half * 32 + i0 + r] * invn[64 + half * 32 + j0 + c];
                if (half == 0) Mmat[i0 + r][j0 + c] = v;
                else           Gmat[i0 + r][j0 + c] = v;
            }
        __syncthreads();
    }

    // ---- soft DP with logsumexp ----
    for (int i = t; i < 33 * 34; i += 256) dpb[i] = 0.f;
    __syncthreads();
    for (int d = 2; d <= 64; ++d) {
        int i = t + 1;
        int j = d - i;
        if (t < 32 && j >= 1 && j <= 32) {
            float m = Mmat[i - 1][j - 1];
            float g = Gmat[i - 1][j - 1];
            float x0 = dpb[(i - 1) * 34 + (j - 1)] * 10.0f;          // /GAMMA
            float x1 = (g + dpb[(i - 1) * 34 + j]) * 10.0f;
            float x2 = (g + dpb[i * 34 + (j - 1)]) * 10.0f;
            float mx = fmaxf(x0, fmaxf(x1, x2));
            float lse = mx + logf(expf(x0 - mx) + expf(x1 - mx) + expf(x2 - mx));
            dpb[i * 34 + j] = m + 0.1f * lse;
        }
        __syncthreads();
    }
    if (t == 0) fsd_out[b] = dpb[32 * 34 + 32];
}

// ---------------- final combine ----------------
__device__ float block_reduce(float v, float* red, int t) {
    red[t] = v;
    __syncthreads();
    for (int o = 128; o; o >>= 1) {
        if (t < o) red[t] += red[t + o];
        __syncthreads();
    }
    float r = red[0];
    __syncthreads();
    return r;
}

__global__ __launch_bounds__(256) void final_kernel(
    const float* __restrict__ ai0, const float* __restrict__ ac0,
    const float* __restrict__ ab0, const float* __restrict__ vid0,
    const float* __restrict__ ai1, const float* __restrict__ ac1,
    const float* __restrict__ ab1, const float* __restrict__ vid1,
    const float* __restrict__ ws, float* __restrict__ out) {
    __shared__ float rs0[Bn], rs1[Bn];
    __shared__ float red[256];
    int t = threadIdx.x;
    if (t < Bn) {
        float s0 = 0.f, s1 = 0.f;
        for (int c = 0; c < NCLS; ++c) { s0 += vid0[t * NCLS + c]; s1 += vid1[t * NCLS + c]; }
        rs0[t] = s0;
        rs1[t] = s1;
    }
    __syncthreads();

    float inst0 = 0.f, cont0 = 0.f, back0 = 0.f;
    float inst1 = 0.f, cont1 = 0.f, back1 = 0.f;
    for (int idx = t; idx < Bn * (NCLS + 1); idx += 256) {
        int b = idx / (NCLS + 1), c = idx % (NCLS + 1);
        float v0 = (c < NCLS) ? vid0[b * NCLS + c] : 0.f;
        float v1 = (c < NCLS) ? vid1[b * NCLS + c] : 0.f;
        float wI0 = (c < NCLS) ? (v0 / rs0[b]) : 0.f;
        float wC0 = ((c < NCLS) ? v0 : 1.f) / (rs0[b] + 1.f);
        float wI1 = (c < NCLS) ? (v1 / rs1[b]) : 0.f;
        float wC1 = ((c < NCLS) ? v1 : 1.f) / (rs1[b] + 1.f);
        inst0 += logf(ai0[idx] + 1e-10f) * wI0;
        cont0 += logf(ac0[idx] + 1e-10f) * wC0;
        inst1 += logf(ai1[idx] + 1e-10f) * wI1;
        cont1 += logf(ac1[idx] + 1e-10f) * wC1;
        if (c == NCLS) {
            back0 += logf(ab0[idx] + 1e-10f);
            back1 += logf(ab1[idx] + 1e-10f);
        }
    }
    float sInst0 = block_reduce(inst0, red, t);
    float sCont0 = block_reduce(cont0, red, t);
    float sBack0 = block_reduce(back0, red, t);
    float sInst1 = block_reduce(inst1, red, t);
    float sCont1 = block_reduce(cont1, red, t);
    float sBack1 = block_reduce(back1, red, t);

    // feat losses
    float fv0 = 0.f, fv1 = 0.f;
    if (t < Bn) {
        const float* nm = ws + WS_NORM;
        {
            float ni = nm[0 * Bn + t], nc = nm[1 * Bn + t], nb = nm[2 * Bn + t];
            float f1 = fmaxf(50.0f - ni + nc, 0.f);
            float f2 = fmaxf(50.0f - nc + nb, 0.f);
            float f = f1 + f2 + nb;
            fv0 = f * f;
        }
        {
            float ni = nm[3 * Bn + t], nc = nm[4 * Bn + t], nb = nm[5 * Bn + t];
            float f1 = fmaxf(50.0f - ni + nc, 0.f);
            float f2 = fmaxf(50.0f - nc + nb, 0.f);
            float f = f1 + f2 + nb;
            fv1 = f * f;
        }
    }
    float sFeat0 = block_reduce(fv0, red, t) / (float)Bn;
    float sFeat1 = block_reduce(fv1, red, t) / (float)Bn;

    // pair losses
    float posL = 0.f, negL = 0.f, posF = 0.f, negF = 0.f, pln = 0.f;
    if (t < Bn) {
        float pl = ws[WS_PAIR + t];
        float lv = ws[WS_LCS + t];
        float fv = ws[WS_FSD + t];
        posL = lv * pl; negL = lv * (1.f - pl);
        posF = fv * pl; negF = fv * (1.f - pl);
        pln = pl;
    }
    float sPosL = block_reduce(posL, red, t);
    float sNegL = block_reduce(negL, red, t);
    float sPosF = block_reduce(posF, red, t);
    float sNegF = block_reduce(negF, red, t);
    float sPln = block_reduce(pln, red, t);

    if (t == 0) {
        float cls0 = -(sInst0 + sCont0 + sBack0) / (float)Bn;
        float cls1 = -(sInst1 + sCont1 + sBack1) / (float)Bn;
        float guide0 = ws[WS_ACC + 0] / (float)Bn;
        float sparse0 = ws[WS_ACC + 1] / (float)(Bn * 2);
        float guide1 = ws[WS_ACC + 2] / (float)Bn;
        float sparse1 = ws[WS_ACC + 3] / (float)(Bn * 2);
        float loss0 = cls0 + 1.0f * guide0 + 5e-05f * sFeat0 + 8e-05f * sparse0;
        float loss1 = cls1 + 1.0f * guide1 + 5e-05f * sFeat1 + 8e-05f * sparse1;
        float acm = 0.5f * (loss0 + loss1);
        float posn = sPln;
        float negn = (float)Bn - posn;
        float lcs_loss = sNegL / (negn + 1e-10f) - sPosL / (posn + 1e-10f);
        float fsd_loss = sNegF / (negn + 1e-10f) - sPosF / (posn + 1e-10f);
        out[0] = acm + 0.01f * lcs_loss + 0.01f * fsd_loss;
    }
}

extern "C" void kernel_launch(void* const* d_in, const int* in_sizes, int n_in,
                              void* d_out, int out_size, void* d_ws, size_t ws_size,
                              hipStream_t stream) {
    (void)in_sizes; (void)n_in; (void)out_size; (void)ws_size;
    const float* ai0  = (const float*)d_in[0];
    const float* ac0  = (const float*)d_in[1];
    const float* ab0  = (const float*)d_in[2];
    const float* vid0 = (const float*)d_in[3];
    const float* att0 = (const float*)d_in[4];
    const float* fi0  = (const float*)d_in[5];
    const float* fc0  = (const float*)d_in[6];
    const float* fb0  = (const float*)d_in[7];
    const float* cas0 = (const float*)d_in[8];
    const float* lcs0 = (const float*)d_in[9];
    const float* fsdA0 = (const float*)d_in[10];
    // d_in[11] = fsd_bak_candi_0 (unused by reference)
    const float* ai1  = (const float*)d_in[12];
    const float* ac1  = (const float*)d_in[13];
    const float* ab1  = (const float*)d_in[14];
    const float* vid1 = (const float*)d_in[15];
    const float* att1 = (const float*)d_in[16];
    const float* fi1  = (const float*)d_in[17];
    const float* fc1  = (const float*)d_in[18];
    const float* fb1  = (const float*)d_in[19];
    const float* cas1 = (const float*)d_in[20];
    const float* lcs1 = (const float*)d_in[21];
    const float* fsdA1 = (const float*)d_in[22];
    const float* fsdB1 = (const float*)d_in[23];

    float* ws = (float*)d_ws;

    hipMemsetAsync(d_ws, 0, 4 * sizeof(float), stream);  // zero atomic accumulators
    pair_kernel<<<1, 64, 0, stream>>>(vid0, vid1, ws + WS_PAIR);
    guide_sparse_kernel<<<512, 256, 0, stream>>>(cas0, att0, cas1, att1, ws + WS_ACC);
    featnorm_kernel<<<6 * Bn, 256, 0, stream>>>(fi0, fc0, fb0, fi1, fc1, fb1, ws + WS_NORM);
    lcs_kernel<<<Bn, 256, 0, stream>>>(lcs0, lcs1, ws + WS_LCS);
    fsd_kernel<<<Bn, 256, 0, stream>>>(fsdA0, fsdA1, fsdB1, ws + WS_PAIR, ws + WS_FSD);
    final_kernel<<<1, 256, 0, stream>>>(ai0, ac0, ab0, vid0, ai1, ac1, ab1, vid1, ws,
                                        (float*)d_out);
}

// Round 2
// 336.474 us; speedup vs baseline: 3.0763x; 3.0763x over previous
//
#include <hip/hip_runtime.h>
#include <math.h>

#define Bn 64
#define Tn 2048
#define NCLS 20
#define Dn 2048
#define LCSL 64
#define FSDL 32

// ws float offsets
#define WS_ACC 0        // 4 floats: guide0, sparse0, guide1, sparse1 (atomic accumulators)
#define WS_PAIR 4       // 64
#define WS_LCS 68       // 64
#define WS_FSD 132      // 64
#define WS_NORM 196     // 6*64 = 384 (feat norms)
#define WS_LCSN 580     // 2*64*64 = 8192 (lcs inv norms [tensor][b][row])
#define WS_FSDN 8772    // 3*64*2*32 = 12288 (fsd inv norms [tensor][b][half][row])
#define WS_SPART 21060  // 4*64*64*64 = 1048576 (lcs S partials [ks][b][i][j])
#define WS_MG 1069636   // 64*2*32*32 = 131072 (fsd normalized M,G [b][half][i][j])

// ---------------- pair label ----------------
__global__ void pair_kernel(const float* __restrict__ vid0, const float* __restrict__ vid1,
                            float* __restrict__ pl) {
    int b = threadIdx.x;
    if (b < Bn) {
        float s = 0.f;
        for (int c = 0; c < NCLS; ++c) s += vid0[b * NCLS + c] * vid1[b * NCLS + c];
        pl[b] = (s > 0.f) ? 1.f : 0.f;
    }
}

// ---------------- LCS inverse norms: 8192 rows of 2048, wave per row ----------------
__global__ __launch_bounds__(256) void lcs_norm_kernel(const float* __restrict__ c0,
                                                       const float* __restrict__ c1,
                                                       float* __restrict__ invn) {
    int R = blockIdx.x * 4 + (threadIdx.x >> 6);  // 0..8191
    int lane = threadIdx.x & 63;
    const float* base = (R < 4096) ? c0 : c1;
    int r = R & 4095;
    const float* p = base + (size_t)r * Dn;
    float s = 0.f;
    #pragma unroll
    for (int q = 0; q < 8; ++q) {
        float4 v = *(const float4*)(p + q * 256 + lane * 4);
        s += v.x * v.x + v.y * v.y + v.z * v.z + v.w * v.w;
    }
    for (int off = 32; off; off >>= 1) s += __shfl_down(s, off);
    if (lane == 0) invn[R] = 1.0f / sqrtf(s);
}

// ---------------- FSD inverse norms: 3 tensors x 64 b x 2 half x 32 rows of 1024 ----------------
__global__ __launch_bounds__(256) void fsd_norm_kernel(const float* __restrict__ a0,
                                                       const float* __restrict__ a1,
                                                       const float* __restrict__ b1,
                                                       float* __restrict__ invn) {
    int Q = blockIdx.x * 4 + (threadIdx.x >> 6);  // 0..12287
    int lane = threadIdx.x & 63;
    int tensor = Q >> 12;
    int rem = Q & 4095;
    int b = rem >> 6, half = (rem >> 5) & 1, row = rem & 31;
    const float* base = (tensor == 0) ? a0 : ((tensor == 1) ? a1 : b1);
    const float* p = base + ((size_t)b * FSDL + row) * Dn + half * 1024;
    float s = 0.f;
    #pragma unroll
    for (int q = 0; q < 4; ++q) {
        float4 v = *(const float4*)(p + q * 256 + lane * 4);
        s += v.x * v.x + v.y * v.y + v.z * v.z + v.w * v.w;
    }
    for (int off = 32; off; off >>= 1) s += __shfl_down(s, off);
    if (lane == 0) invn[Q] = 1.0f / sqrtf(s);
}

// ---------------- guide + sparse reduction ----------------
__global__ __launch_bounds__(256) void guide_sparse_kernel(
    const float* __restrict__ cas0, const float* __restrict__ att0,
    const float* __restrict__ cas1, const float* __restrict__ att1,
    float* __restrict__ acc) {
    const int N = Bn * Tn;
    float g0 = 0.f, s0 = 0.f, g1 = 0.f, s1 = 0.f;
    for (int n = blockIdx.x * blockDim.x + threadIdx.x; n < 2 * N;
         n += gridDim.x * blockDim.x) {
        int sfx = (n >= N);
        int m = sfx ? (n - N) : n;
        const float* cas = sfx ? cas1 : cas0;
        const float* att = sfx ? att1 : att0;
        float a0 = att[m * 3 + 0];
        float a1 = att[m * 3 + 1];
        float g = fabsf(1.0f - cas[m * (NCLS + 1) + NCLS] - a0);
        float s = a0 + a1;
        if (sfx) { g1 += g; s1 += s; } else { g0 += g; s0 += s; }
    }
    __shared__ float red[256];
    float vals[4] = {g0, s0, g1, s1};
    for (int v = 0; v < 4; ++v) {
        red[threadIdx.x] = vals[v];
        __syncthreads();
        for (int o = 128; o; o >>= 1) {
            if ((int)threadIdx.x < o) red[threadIdx.x] += red[threadIdx.x + o];
            __syncthreads();
        }
        if (threadIdx.x == 0) atomicAdd(&acc[v], red[0]);
        __syncthreads();
    }
}

// ---------------- feature norms ----------------
__global__ __launch_bounds__(256) void featnorm_kernel(
    const float* __restrict__ f0, const float* __restrict__ f1, const float* __restrict__ f2,
    const float* __restrict__ f3, const float* __restrict__ f4, const float* __restrict__ f5,
    float* __restrict__ norms) {
    int f = blockIdx.x / Bn;
    int row = blockIdx.x % Bn;
    const float* arr[6] = {f0, f1, f2, f3, f4, f5};
    const float* p = arr[f] + (size_t)row * Dn;
    float s = 0.f;
    for (int k = threadIdx.x * 4; k < Dn; k += 1024) {
        float4 v = *(const float4*)(p + k);
        s += v.x * v.x + v.y * v.y + v.z * v.z + v.w * v.w;
    }
    __shared__ float red[256];
    red[threadIdx.x] = s;
    __syncthreads();
    for (int o = 128; o; o >>= 1) {
        if ((int)threadIdx.x < o) red[threadIdx.x] += red[threadIdx.x + o];
        __syncthreads();
    }
    if (threadIdx.x == 0) norms[f * Bn + row] = sqrtf(red[0]);
}

// ---------------- LCS GEMM (K-split 4): partial S into ws ----------------
__global__ __launch_bounds__(256) void lcs_gemm_kernel(const float* __restrict__ cand0,
                                                       const float* __restrict__ cand1,
                                                       float* __restrict__ spart) {
    const int b = blockIdx.x >> 2;
    const int ks = blockIdx.x & 3;
    const float* c0 = cand0 + (size_t)b * LCSL * Dn + ks * 512;
    const float* c1 = cand1 + (size_t)b * LCSL * Dn + ks * 512;

    __shared__ float tA[64 * 66];  // [k][row] pad 66 (even: aligned b64, 2-way reads)
    __shared__ float tB[64 * 66];

    const int t = threadIdx.x;
    const int ti = t >> 4, tj = t & 15;
    const int i0 = ti * 4, j0 = tj * 4;
    float acc[4][4] = {};

    for (int kc = 0; kc < 512; kc += 64) {
        #pragma unroll
        for (int l = 0; l < 4; ++l) {
            int idx4 = l * 256 + t;       // 1024 float4 slots = 64 rows x 16
            int row = idx4 >> 4;
            int kq = (idx4 & 15) * 4;
            float4 av = *(const float4*)(c0 + (size_t)row * Dn + kc + kq);
            float4 bv = *(const float4*)(c1 + (size_t)row * Dn + kc + kq);
            tA[(kq + 0) * 66 + row] = av.x;
            tA[(kq + 1) * 66 + row] = av.y;
            tA[(kq + 2) * 66 + row] = av.z;
            tA[(kq + 3) * 66 + row] = av.w;
            tB[(kq + 0) * 66 + row] = bv.x;
            tB[(kq + 1) * 66 + row] = bv.y;
            tB[(kq + 2) * 66 + row] = bv.z;
            tB[(kq + 3) * 66 + row] = bv.w;
        }
        __syncthreads();
        #pragma unroll 8
        for (int k = 0; k < 64; ++k) {
            float2 a0v = *(const float2*)&tA[k * 66 + i0];
            float2 a1v = *(const float2*)&tA[k * 66 + i0 + 2];
            float2 b0v = *(const float2*)&tB[k * 66 + j0];
            float2 b1v = *(const float2*)&tB[k * 66 + j0 + 2];
            float a[4] = {a0v.x, a0v.y, a1v.x, a1v.y};
            float bb[4] = {b0v.x, b0v.y, b1v.x, b1v.y};
            #pragma unroll
            for (int r = 0; r < 4; ++r)
                #pragma unroll
                for (int c = 0; c < 4; ++c)
                    acc[r][c] = fmaf(a[r], bb[c], acc[r][c]);
        }
        __syncthreads();
    }
    float* dst = spart + (size_t)(ks * Bn + b) * 4096;
    #pragma unroll
    for (int r = 0; r < 4; ++r) {
        float4 v = {acc[r][0], acc[r][1], acc[r][2], acc[r][3]};
        *(float4*)(dst + (i0 + r) * 64 + j0) = v;
    }
}

// ---------------- LCS DP (single wave, register wavefront) ----------------
__global__ __launch_bounds__(64) void lcs_dp_kernel(const float* __restrict__ spart,
                                                    const float* __restrict__ invn,
                                                    float* __restrict__ out) {
    const int b = blockIdx.x;
    const int t = threadIdx.x;  // 0..63, lane t handles row i = t+1
    __shared__ float S[64 * 66];
    __shared__ float inv0[64], inv1[64];
    inv0[t] = invn[b * 64 + t];
    inv1[t] = invn[4096 + b * 64 + t];
    __syncthreads();
    for (int idx = t; idx < 4096; idx += 64) {
        int i = idx >> 6, j = idx & 63;
        float s = spart[(size_t)(0 * Bn + b) * 4096 + idx] +
                  spart[(size_t)(1 * Bn + b) * 4096 + idx] +
                  spart[(size_t)(2 * Bn + b) * 4096 + idx] +
                  spart[(size_t)(3 * Bn + b) * 4096 + idx];
        S[i * 66 + j] = s * inv0[i] * inv1[j];
    }
    __syncthreads();

    float prev = 0.f, prevprev = 0.f;
    float sval_next = S[t * 66 + 0];  // s for first active diag d = t+2
    for (int d = 2; d <= 128; ++d) {
        float s = sval_next;
        int jn = d - t - 1;  // (j-1) needed at diag d+1
        if (jn >= 0 && jn < 64) sval_next = S[t * 66 + jn];
        float up = __shfl_up(prev, 1);
        float dg = __shfl_up(prevprev, 1);
        if (t == 0) { up = 0.f; dg = 0.f; }
        int j = d - t - 1;
        float left = prev;
        float val = (s > 0.5f) ? (dg + s) : fmaxf(up, left);
        float cur = (j >= 1 && j <= 64) ? val : 0.f;
        prevprev = prev;
        prev = cur;
    }
    if (t == 63) out[b] = prev;  // dp[64][64]
}

// ---------------- FSD GEMM: normalized M/G into ws ----------------
__global__ __launch_bounds__(256) void fsd_gemm_kernel(const float* __restrict__ act0,
                                                       const float* __restrict__ act1,
                                                       const float* __restrict__ bak1,
                                                       const float* __restrict__ pair,
                                                       const float* __restrict__ invn,
                                                       float* __restrict__ mg) {
    const int b = blockIdx.x >> 1;
    const int half = blockIdx.x & 1;
    const int sel = (pair[b] > 0.f) ? 1 : 2;
    const float* c0 = act0 + (size_t)b * FSDL * Dn + half * 1024;
    const float* c1 = ((sel == 1) ? act1 : bak1) + (size_t)b * FSDL * Dn + half * 1024;
    const float* in0 = invn + 0 * 4096 + b * 64 + half * 32;
    const float* in1 = invn + sel * 4096 + b * 64 + half * 32;

    __shared__ float tA[64 * 34];  // [k][row] pad 34
    __shared__ float tB[64 * 34];

    const int t = threadIdx.x;
    const int ti = t >> 4, tj = t & 15;
    const int i0 = ti * 2, j0 = tj * 2;
    float acc[2][2] = {};

    for (int kc = 0; kc < 1024; kc += 64) {
        #pragma unroll
        for (int l = 0; l < 2; ++l) {
            int idx4 = l * 256 + t;  // 512 slots = 32 rows x 16
            int row = idx4 >> 4;
            int kq = (idx4 & 15) * 4;
            float4 av = *(const float4*)(c0 + (size_t)row * Dn + kc + kq);
            float4 bv = *(const float4*)(c1 + (size_t)row * Dn + kc + kq);
            tA[(kq + 0) * 34 + row] = av.x;
            tA[(kq + 1) * 34 + row] = av.y;
            tA[(kq + 2) * 34 + row] = av.z;
            tA[(kq + 3) * 34 + row] = av.w;
            tB[(kq + 0) * 34 + row] = bv.x;
            tB[(kq + 1) * 34 + row] = bv.y;
            tB[(kq + 2) * 34 + row] = bv.z;
            tB[(kq + 3) * 34 + row] = bv.w;
        }
        __syncthreads();
        #pragma unroll 8
        for (int k = 0; k < 64; ++k) {
            float2 a = *(const float2*)&tA[k * 34 + i0];
            float2 bb = *(const float2*)&tB[k * 34 + j0];
            acc[0][0] = fmaf(a.x, bb.x, acc[0][0]);
            acc[0][1] = fmaf(a.x, bb.y, acc[0][1]);
            acc[1][0] = fmaf(a.y, bb.x, acc[1][0]);
            acc[1][1] = fmaf(a.y, bb.y, acc[1][1]);
        }
        __syncthreads();
    }
    float* dst = mg + (size_t)b * 2048 + half * 1024;
    #pragma unroll
    for (int r = 0; r < 2; ++r)
        #pragma unroll
        for (int c = 0; c < 2; ++c)
            dst[(i0 + r) * 32 + (j0 + c)] = acc[r][c] * in0[i0 + r] * in1[j0 + c];
}

// ---------------- FSD DP (single wave, register wavefront, soft-DP) ----------------
__global__ __launch_bounds__(64) void fsd_dp_kernel(const float* __restrict__ mg,
                                                    float* __restrict__ out) {
    const int b = blockIdx.x;
    const int t = threadIdx.x;
    __shared__ float M[32 * 34], G[32 * 34];
    for (int idx = t; idx < 1024; idx += 64) {
        int i = idx >> 5, j = idx & 31;
        M[i * 34 + j] = mg[(size_t)b * 2048 + idx];
        G[i * 34 + j] = mg[(size_t)b * 2048 + 1024 + idx];
    }
    __syncthreads();
    if (t < 32) {
        float prev = 0.f, prevprev = 0.f;
        float m_next = M[t * 34 + 0], g_next = G[t * 34 + 0];
        for (int d = 2; d <= 64; ++d) {
            float m = m_next, g = g_next;
            int jn = d - t - 1;
            if (jn >= 0 && jn < 32) { m_next = M[t * 34 + jn]; g_next = G[t * 34 + jn]; }
            float up = __shfl_up(prev, 1);
            float dg = __shfl_up(prevprev, 1);
            if (t == 0) { up = 0.f; dg = 0.f; }
            int j = d - t - 1;
            float left = prev;
            float x0 = dg * 10.0f;
            float x1 = (g + up) * 10.0f;
            float x2 = (g + left) * 10.0f;
            float mx = fmaxf(x0, fmaxf(x1, x2));
            float lse = mx + __logf(__expf(x0 - mx) + __expf(x1 - mx) + __expf(x2 - mx));
            float val = m + 0.1f * lse;
            float cur = (j >= 1 && j <= 32) ? val : 0.f;
            prevprev = prev;
            prev = cur;
        }
        if (t == 31) out[b] = prev;  // dp[32][32]
    }
}

// ---------------- final combine ----------------
__device__ float block_reduce(float v, float* red, int t) {
    red[t] = v;
    __syncthreads();
    for (int o = 128; o; o >>= 1) {
        if (t < o) red[t] += red[t + o];
        __syncthreads();
    }
    float r = red[0];
    __syncthreads();
    return r;
}

__global__ __launch_bounds__(256) void final_kernel(
    const float* __restrict__ ai0, const float* __restrict__ ac0,
    const float* __restrict__ ab0, const float* __restrict__ vid0,
    const float* __restrict__ ai1, const float* __restrict__ ac1,
    const float* __restrict__ ab1, const float* __restrict__ vid1,
    const float* __restrict__ ws, float* __restrict__ out) {
    __shared__ float rs0[Bn], rs1[Bn];
    __shared__ float red[256];
    int t = threadIdx.x;
    if (t < Bn) {
        float s0 = 0.f, s1 = 0.f;
        for (int c = 0; c < NCLS; ++c) { s0 += vid0[t * NCLS + c]; s1 += vid1[t * NCLS + c]; }
        rs0[t] = s0;
        rs1[t] = s1;
    }
    __syncthreads();

    float inst0 = 0.f, cont0 = 0.f, back0 = 0.f;
    float inst1 = 0.f, cont1 = 0.f, back1 = 0.f;
    for (int idx = t; idx < Bn * (NCLS + 1); idx += 256) {
        int b = idx / (NCLS + 1), c = idx % (NCLS + 1);
        float v0 = (c < NCLS) ? vid0[b * NCLS + c] : 0.f;
        float v1 = (c < NCLS) ? vid1[b * NCLS + c] : 0.f;
        float wI0 = (c < NCLS) ? (v0 / rs0[b]) : 0.f;
        float wC0 = ((c < NCLS) ? v0 : 1.f) / (rs0[b] + 1.f);
        float wI1 = (c < NCLS) ? (v1 / rs1[b]) : 0.f;
        float wC1 = ((c < NCLS) ? v1 : 1.f) / (rs1[b] + 1.f);
        inst0 += logf(ai0[idx] + 1e-10f) * wI0;
        cont0 += logf(ac0[idx] + 1e-10f) * wC0;
        inst1 += logf(ai1[idx] + 1e-10f) * wI1;
        cont1 += logf(ac1[idx] + 1e-10f) * wC1;
        if (c == NCLS) {
            back0 += logf(ab0[idx] + 1e-10f);
            back1 += logf(ab1[idx] + 1e-10f);
        }
    }
    float sInst0 = block_reduce(inst0, red, t);
    float sCont0 = block_reduce(cont0, red, t);
    float sBack0 = block_reduce(back0, red, t);
    float sInst1 = block_reduce(inst1, red, t);
    float sCont1 = block_reduce(cont1, red, t);
    float sBack1 = block_reduce(back1, red, t);

    float fv0 = 0.f, fv1 = 0.f;
    if (t < Bn) {
        const float* nm = ws + WS_NORM;
        {
            float ni = nm[0 * Bn + t], nc = nm[1 * Bn + t], nb = nm[2 * Bn + t];
            float f1 = fmaxf(50.0f - ni + nc, 0.f);
            float f2 = fmaxf(50.0f - nc + nb, 0.f);
            float f = f1 + f2 + nb;
            fv0 = f * f;
        }
        {
            float ni = nm[3 * Bn + t], nc = nm[4 * Bn + t], nb = nm[5 * Bn + t];
            float f1 = fmaxf(50.0f - ni + nc, 0.f);
            float f2 = fmaxf(50.0f - nc + nb, 0.f);
            float f = f1 + f2 + nb;
            fv1 = f * f;
        }
    }
    float sFeat0 = block_reduce(fv0, red, t) / (float)Bn;
    float sFeat1 = block_reduce(fv1, red, t) / (float)Bn;

    float posL = 0.f, negL = 0.f, posF = 0.f, negF = 0.f, pln = 0.f;
    if (t < Bn) {
        float pl = ws[WS_PAIR + t];
        float lv = ws[WS_LCS + t];
        float fv = ws[WS_FSD + t];
        posL = lv * pl; negL = lv * (1.f - pl);
        posF = fv * pl; negF = fv * (1.f - pl);
        pln = pl;
    }
    float sPosL = block_reduce(posL, red, t);
    float sNegL = block_reduce(negL, red, t);
    float sPosF = block_reduce(posF, red, t);
    float sNegF = block_reduce(negF, red, t);
    float sPln = block_reduce(pln, red, t);

    if (t == 0) {
        float cls0 = -(sInst0 + sCont0 + sBack0) / (float)Bn;
        float cls1 = -(sInst1 + sCont1 + sBack1) / (float)Bn;
        float guide0 = ws[WS_ACC + 0] / (float)Bn;
        float sparse0 = ws[WS_ACC + 1] / (float)(Bn * 2);
        float guide1 = ws[WS_ACC + 2] / (float)Bn;
        float sparse1 = ws[WS_ACC + 3] / (float)(Bn * 2);
        float loss0 = cls0 + 1.0f * guide0 + 5e-05f * sFeat0 + 8e-05f * sparse0;
        float loss1 = cls1 + 1.0f * guide1 + 5e-05f * sFeat1 + 8e-05f * sparse1;
        float acm = 0.5f * (loss0 + loss1);
        float posn = sPln;
        float negn = (float)Bn - posn;
        float lcs_loss = sNegL / (negn + 1e-10f) - sPosL / (posn + 1e-10f);
        float fsd_loss = sNegF / (negn + 1e-10f) - sPosF / (posn + 1e-10f);
        out[0] = acm + 0.01f * lcs_loss + 0.01f * fsd_loss;
    }
}

extern "C" void kernel_launch(void* const* d_in, const int* in_sizes, int n_in,
                              void* d_out, int out_size, void* d_ws, size_t ws_size,
                              hipStream_t stream) {
    (void)in_sizes; (void)n_in; (void)out_size; (void)ws_size;
    const float* ai0  = (const float*)d_in[0];
    const float* ac0  = (const float*)d_in[1];
    const float* ab0  = (const float*)d_in[2];
    const float* vid0 = (const float*)d_in[3];
    const float* att0 = (const float*)d_in[4];
    const float* fi0  = (const float*)d_in[5];
    const float* fc0  = (const float*)d_in[6];
    const float* fb0  = (const float*)d_in[7];
    const float* cas0 = (const float*)d_in[8];
    const float* lcs0 = (const float*)d_in[9];
    const float* fsdA0 = (const float*)d_in[10];
    const float* ai1  = (const float*)d_in[12];
    const float* ac1  = (const float*)d_in[13];
    const float* ab1  = (const float*)d_in[14];
    const float* vid1 = (const float*)d_in[15];
    const float* att1 = (const float*)d_in[16];
    const float* fi1  = (const float*)d_in[17];
    const float* fc1  = (const float*)d_in[18];
    const float* fb1  = (const float*)d_in[19];
    const float* cas1 = (const float*)d_in[20];
    const float* lcs1 = (const float*)d_in[21];
    const float* fsdA1 = (const float*)d_in[22];
    const float* fsdB1 = (const float*)d_in[23];

    float* ws = (float*)d_ws;

    hipMemsetAsync(d_ws, 0, 4 * sizeof(float), stream);  // zero atomic accumulators
    pair_kernel<<<1, 64, 0, stream>>>(vid0, vid1, ws + WS_PAIR);
    lcs_norm_kernel<<<2048, 256, 0, stream>>>(lcs0, lcs1, ws + WS_LCSN);
    fsd_norm_kernel<<<3072, 256, 0, stream>>>(fsdA0, fsdA1, fsdB1, ws + WS_FSDN);
    featnorm_kernel<<<6 * Bn, 256, 0, stream>>>(fi0, fc0, fb0, fi1, fc1, fb1, ws + WS_NORM);
    guide_sparse_kernel<<<512, 256, 0, stream>>>(cas0, att0, cas1, att1, ws + WS_ACC);
    lcs_gemm_kernel<<<Bn * 4, 256, 0, stream>>>(lcs0, lcs1, ws + WS_SPART);
    lcs_dp_kernel<<<Bn, 64, 0, stream>>>(ws + WS_SPART, ws + WS_LCSN, ws + WS_LCS);
    fsd_gemm_kernel<<<Bn * 2, 256, 0, stream>>>(fsdA0, fsdA1, fsdB1, ws + WS_PAIR,
                                                ws + WS_FSDN, ws + WS_MG);
    fsd_dp_kernel<<<Bn, 64, 0, stream>>>(ws + WS_MG, ws + WS_FSD);
    final_kernel<<<1, 256, 0, stream>>>(ai0, ac0, ab0, vid0, ai1, ac1, ab1, vid1, ws,
                                        (float*)d_out);
}

// Round 3
// 271.688 us; speedup vs baseline: 3.8099x; 1.2385x over previous
//
#include <hip/hip_runtime.h>
#include <math.h>

#define Bn 64
#define Tn 2048
#define NCLS 20
#define Dn 2048
#define LCSL 64
#define FSDL 32

#define KS_L 8   // LCS K-split (K=256 per block)
#define KS_F 4   // FSD K-split (K=256 per block)

// ws float offsets
#define WS_ACC 0        // 4 floats: guide0, sparse0, guide1, sparse1 (atomics)
#define WS_PAIR 4       // 64
#define WS_LCS 68       // 64
#define WS_FSD 132      // 64
#define WS_NORM 196     // 384 feat norms
#define WS_LSQ 580      // 8*64*128 = 65536   partial sumsq [ks][b][tensor][64]
#define WS_FSQ 66116    // 4*64*128 = 32768   partial sumsq [ks][b][half][tensor][32]
#define WS_SPART 98884  // 8*64*4096 = 2097152  LCS S partials [ks][b][i*64+j]
#define WS_MG 2196036   // 4*64*2*1024 = 524288  FSD partials [ks][b][half][i*32+j]

// ============ fused small: guide/sparse + featnorm + pair ============
__global__ __launch_bounds__(256) void fused_small_kernel(
    const float* __restrict__ cas0, const float* __restrict__ att0,
    const float* __restrict__ cas1, const float* __restrict__ att1,
    const float* __restrict__ f0, const float* __restrict__ f1,
    const float* __restrict__ f2, const float* __restrict__ f3,
    const float* __restrict__ f4, const float* __restrict__ f5,
    const float* __restrict__ vid0, const float* __restrict__ vid1,
    float* __restrict__ ws) {
    const int gb = blockIdx.x;
    const int t = threadIdx.x;
    if (gb < 512) {
        // ---- guide + sparse ----
        const int N = Bn * Tn;
        float g0 = 0.f, s0 = 0.f, g1 = 0.f, s1 = 0.f;
        for (int n = gb * 256 + t; n < 2 * N; n += 512 * 256) {
            int sfx = (n >= N);
            int m = sfx ? (n - N) : n;
            const float* cas = sfx ? cas1 : cas0;
            const float* att = sfx ? att1 : att0;
            float a0 = att[m * 3 + 0];
            float a1 = att[m * 3 + 1];
            float g = fabsf(1.0f - cas[m * (NCLS + 1) + NCLS] - a0);
            float s = a0 + a1;
            if (sfx) { g1 += g; s1 += s; } else { g0 += g; s0 += s; }
        }
        __shared__ float red[256];
        float vals[4] = {g0, s0, g1, s1};
        for (int v = 0; v < 4; ++v) {
            red[t] = vals[v];
            __syncthreads();
            for (int o = 128; o; o >>= 1) {
                if (t < o) red[t] += red[t + o];
                __syncthreads();
            }
            if (t == 0) atomicAdd(&ws[WS_ACC + v], red[0]);
            __syncthreads();
        }
    } else if (gb < 608) {
        // ---- feat norms: 384 rows, wave per row ----
        int R = (gb - 512) * 4 + (t >> 6);
        int lane = t & 63;
        const float* arr[6] = {f0, f1, f2, f3, f4, f5};
        const float* p = arr[R >> 6] + (size_t)(R & 63) * Dn;
        float s = 0.f;
        #pragma unroll
        for (int q = 0; q < 8; ++q) {
            float4 v = *(const float4*)(p + q * 256 + lane * 4);
            s += v.x * v.x + v.y * v.y + v.z * v.z + v.w * v.w;
        }
        for (int off = 32; off; off >>= 1) s += __shfl_down(s, off);
        if (lane == 0) ws[WS_NORM + R] = sqrtf(s);
    } else {
        // ---- pair label ----
        if (t < Bn) {
            float s = 0.f;
            for (int c = 0; c < NCLS; ++c) s += vid0[t * NCLS + c] * vid1[t * NCLS + c];
            ws[WS_PAIR + t] = (s > 0.f) ? 1.f : 0.f;
        }
    }
}

// ============ fused GEMM: LCS (blocks 0..511) + FSD (512..1023) ============
__global__ __launch_bounds__(256) void gemm_kernel(const float* __restrict__ cand0,
                                                   const float* __restrict__ cand1,
                                                   const float* __restrict__ act0,
                                                   const float* __restrict__ act1,
                                                   const float* __restrict__ bak1,
                                                   float* __restrict__ ws) {
    __shared__ float tA[64 * 66];
    __shared__ float tB[64 * 66];
    const int t = threadIdx.x;

    if (blockIdx.x < 512) {
        // -------- LCS partial GEMM: block = (b, ks), K = 256 --------
        const int b = blockIdx.x >> 3;
        const int ks = blockIdx.x & 7;
        const float* c0 = cand0 + (size_t)b * LCSL * Dn + ks * 256;
        const float* c1 = cand1 + (size_t)b * LCSL * Dn + ks * 256;

        const int ti = t >> 4, tj = t & 15;
        const int i0 = ti * 4, j0 = tj * 4;
        float acc[4][4] = {};
        float sqa[4] = {}, sqb[4] = {};

        for (int kc = 0; kc < 256; kc += 64) {
            #pragma unroll
            for (int l = 0; l < 4; ++l) {
                int idx4 = l * 256 + t;          // 1024 slots = 64 rows x 16
                int row = idx4 >> 4;
                int kq = (idx4 & 15) * 4;
                float4 av = *(const float4*)(c0 + (size_t)row * Dn + kc + kq);
                float4 bv = *(const float4*)(c1 + (size_t)row * Dn + kc + kq);
                tA[(kq + 0) * 66 + row] = av.x;
                tA[(kq + 1) * 66 + row] = av.y;
                tA[(kq + 2) * 66 + row] = av.z;
                tA[(kq + 3) * 66 + row] = av.w;
                tB[(kq + 0) * 66 + row] = bv.x;
                tB[(kq + 1) * 66 + row] = bv.y;
                tB[(kq + 2) * 66 + row] = bv.z;
                tB[(kq + 3) * 66 + row] = bv.w;
                sqa[l] += av.x * av.x + av.y * av.y + av.z * av.z + av.w * av.w;
                sqb[l] += bv.x * bv.x + bv.y * bv.y + bv.z * bv.z + bv.w * bv.w;
            }
            __syncthreads();
            #pragma unroll 8
            for (int k = 0; k < 64; ++k) {
                float2 a0v = *(const float2*)&tA[k * 66 + i0];
                float2 a1v = *(const float2*)&tA[k * 66 + i0 + 2];
                float2 b0v = *(const float2*)&tB[k * 66 + j0];
                float2 b1v = *(const float2*)&tB[k * 66 + j0 + 2];
                float a[4] = {a0v.x, a0v.y, a1v.x, a1v.y};
                float bb[4] = {b0v.x, b0v.y, b1v.x, b1v.y};
                #pragma unroll
                for (int r = 0; r < 4; ++r)
                    #pragma unroll
                    for (int c = 0; c < 4; ++c)
                        acc[r][c] = fmaf(a[r], bb[c], acc[r][c]);
            }
            __syncthreads();
        }
        float* dst = ws + WS_SPART + (size_t)(ks * Bn + b) * 4096;
        #pragma unroll
        for (int r = 0; r < 4; ++r) {
            float4 v = {acc[r][0], acc[r][1], acc[r][2], acc[r][3]};
            *(float4*)(dst + (i0 + r) * 64 + j0) = v;
        }
        // partial sumsq: reduce across the 16 lanes sharing a row
        #pragma unroll
        for (int l = 0; l < 4; ++l) {
            float sa = sqa[l], sb = sqb[l];
            for (int m = 1; m < 16; m <<= 1) {
                sa += __shfl_xor(sa, m);
                sb += __shfl_xor(sb, m);
            }
            if ((t & 15) == 0) {
                int row = l * 16 + (t >> 4);
                ws[WS_LSQ + ks * 8192 + b * 128 + row] = sa;
                ws[WS_LSQ + ks * 8192 + b * 128 + 64 + row] = sb;
            }
        }
    } else {
        // -------- FSD partial GEMM: block = (b, half, ks), K = 256 --------
        const int q = blockIdx.x - 512;
        const int b = q >> 3;
        const int half = (q >> 2) & 1;
        const int ks = q & 3;
        const float* pairp = ws + WS_PAIR;
        const int sel = (pairp[b] > 0.f) ? 1 : 2;
        const float* c0 = act0 + (size_t)b * FSDL * Dn + half * 1024 + ks * 256;
        const float* c1 = ((sel == 1) ? act1 : bak1) + (size_t)b * FSDL * Dn + half * 1024 + ks * 256;

        const int ti = t >> 4, tj = t & 15;
        const int i0 = ti * 2, j0 = tj * 2;
        float acc[2][2] = {};
        float sqa[2] = {}, sqb[2] = {};

        for (int kc = 0; kc < 256; kc += 64) {
            #pragma unroll
            for (int l = 0; l < 2; ++l) {
                int idx4 = l * 256 + t;          // 512 slots = 32 rows x 16
                int row = idx4 >> 4;
                int kq = (idx4 & 15) * 4;
                float4 av = *(const float4*)(c0 + (size_t)row * Dn + kc + kq);
                float4 bv = *(const float4*)(c1 + (size_t)row * Dn + kc + kq);
                tA[(kq + 0) * 34 + row] = av.x;
                tA[(kq + 1) * 34 + row] = av.y;
                tA[(kq + 2) * 34 + row] = av.z;
                tA[(kq + 3) * 34 + row] = av.w;
                tB[(kq + 0) * 34 + row] = bv.x;
                tB[(kq + 1) * 34 + row] = bv.y;
                tB[(kq + 2) * 34 + row] = bv.z;
                tB[(kq + 3) * 34 + row] = bv.w;
                sqa[l] += av.x * av.x + av.y * av.y + av.z * av.z + av.w * av.w;
                sqb[l] += bv.x * bv.x + bv.y * bv.y + bv.z * bv.z + bv.w * bv.w;
            }
            __syncthreads();
            #pragma unroll 8
            for (int k = 0; k < 64; ++k) {
                float2 a = *(const float2*)&tA[k * 34 + i0];
                float2 bb = *(const float2*)&tB[k * 34 + j0];
                acc[0][0] = fmaf(a.x, bb.x, acc[0][0]);
                acc[0][1] = fmaf(a.x, bb.y, acc[0][1]);
                acc[1][0] = fmaf(a.y, bb.x, acc[1][0]);
                acc[1][1] = fmaf(a.y, bb.y, acc[1][1]);
            }
            __syncthreads();
        }
        float* dst = ws + WS_MG + (size_t)ks * 131072 + b * 2048 + half * 1024;
        #pragma unroll
        for (int r = 0; r < 2; ++r) {
            float2 v = {acc[r][0], acc[r][1]};
            *(float2*)(dst + (i0 + r) * 32 + j0) = v;
        }
        #pragma unroll
        for (int l = 0; l < 2; ++l) {
            float sa = sqa[l], sb = sqb[l];
            for (int m = 1; m < 16; m <<= 1) {
                sa += __shfl_xor(sa, m);
                sb += __shfl_xor(sb, m);
            }
            if ((t & 15) == 0) {
                int row = l * 16 + (t >> 4);
                ws[WS_FSQ + ks * 8192 + b * 128 + half * 64 + row] = sa;
                ws[WS_FSQ + ks * 8192 + b * 128 + half * 64 + 32 + row] = sb;
            }
        }
    }
}

// ============ fused DP: LCS (blocks 0..63) + FSD (64..127) ============
__global__ __launch_bounds__(64) void dp_kernel(float* __restrict__ ws) {
    const int t = threadIdx.x;
    if (blockIdx.x < 64) {
        const int b = blockIdx.x;
        __shared__ float S[64 * 66];
        __shared__ float i0s[64], i1s[64];
        {
            float s0 = 0.f, s1 = 0.f;
            #pragma unroll
            for (int ks = 0; ks < KS_L; ++ks) {
                s0 += ws[WS_LSQ + ks * 8192 + b * 128 + t];
                s1 += ws[WS_LSQ + ks * 8192 + b * 128 + 64 + t];
            }
            i0s[t] = 1.0f / sqrtf(s0);
            i1s[t] = 1.0f / sqrtf(s1);
        }
        __syncthreads();
        const float* sp = ws + WS_SPART + b * 4096;
        for (int qd = 0; qd < 16; ++qd) {
            int idx4 = t + 64 * qd;          // 1024 float4 slots
            int i = idx4 >> 4;
            int j = (idx4 & 15) * 4;
            float4 v = {0.f, 0.f, 0.f, 0.f};
            #pragma unroll
            for (int ks = 0; ks < KS_L; ++ks) {
                float4 p = *(const float4*)(sp + (size_t)ks * 262144 + idx4 * 4);
                v.x += p.x; v.y += p.y; v.z += p.z; v.w += p.w;
            }
            float ri = i0s[i];
            S[i * 66 + j + 0] = v.x * ri * i1s[j + 0];
            S[i * 66 + j + 1] = v.y * ri * i1s[j + 1];
            S[i * 66 + j + 2] = v.z * ri * i1s[j + 2];
            S[i * 66 + j + 3] = v.w * ri * i1s[j + 3];
        }
        __syncthreads();
        float prev = 0.f, prevprev = 0.f;
        float sval_next = S[t * 66 + 0];
        for (int d = 2; d <= 128; ++d) {
            float s = sval_next;
            int jn = d - t - 1;
            if (jn >= 0 && jn < 64) sval_next = S[t * 66 + jn];
            float up = __shfl_up(prev, 1);
            float dg = __shfl_up(prevprev, 1);
            if (t == 0) { up = 0.f; dg = 0.f; }
            int j = d - t - 1;
            float left = prev;
            float val = (s > 0.5f) ? (dg + s) : fmaxf(up, left);
            float cur = (j >= 1 && j <= 64) ? val : 0.f;
            prevprev = prev;
            prev = cur;
        }
        if (t == 63) ws[WS_LCS + b] = prev;
    } else {
        const int b = blockIdx.x - 64;
        __shared__ float M[32 * 34], G[32 * 34];
        __shared__ float inv[128];  // [half][tensor][32]
        {
            #pragma unroll
            for (int e2 = 0; e2 < 2; ++e2) {
                int e = t + e2 * 64;
                float s = 0.f;
                #pragma unroll
                for (int ks = 0; ks < KS_F; ++ks)
                    s += ws[WS_FSQ + ks * 8192 + b * 128 + e];
                inv[e] = 1.0f / sqrtf(s);
            }
        }
        __syncthreads();
        const float* mg = ws + WS_MG + b * 2048;
        for (int qd = 0; qd < 4; ++qd) {
            int idx4 = t + 64 * qd;          // 256 float4 slots per half
            int i = idx4 >> 3;
            int j = (idx4 & 7) * 4;
            float4 vM = {0.f, 0.f, 0.f, 0.f}, vG = {0.f, 0.f, 0.f, 0.f};
            #pragma unroll
            for (int ks = 0; ks < KS_F; ++ks) {
                float4 pM = *(const float4*)(mg + (size_t)ks * 131072 + idx4 * 4);
                float4 pG = *(const float4*)(mg + (size_t)ks * 131072 + 1024 + idx4 * 4);
                vM.x += pM.x; vM.y += pM.y; vM.z += pM.z; vM.w += pM.w;
                vG.x += pG.x; vG.y += pG.y; vG.z += pG.z; vG.w += pG.w;
            }
            float riM = inv[i], riG = inv[64 + i];
            M[i * 34 + j + 0] = vM.x * riM * inv[32 + j + 0];
            M[i * 34 + j + 1] = vM.y * riM * inv[32 + j + 1];
            M[i * 34 + j + 2] = vM.z * riM * inv[32 + j + 2];
            M[i * 34 + j + 3] = vM.w * riM * inv[32 + j + 3];
            G[i * 34 + j + 0] = vG.x * riG * inv[96 + j + 0];
            G[i * 34 + j + 1] = vG.y * riG * inv[96 + j + 1];
            G[i * 34 + j + 2] = vG.z * riG * inv[96 + j + 2];
            G[i * 34 + j + 3] = vG.w * riG * inv[96 + j + 3];
        }
        __syncthreads();
        if (t < 32) {
            float prev = 0.f, prevprev = 0.f;
            float m_next = M[t * 34 + 0], g_next = G[t * 34 + 0];
            for (int d = 2; d <= 64; ++d) {
                float m = m_next, g = g_next;
                int jn = d - t - 1;
                if (jn >= 0 && jn < 32) { m_next = M[t * 34 + jn]; g_next = G[t * 34 + jn]; }
                float up = __shfl_up(prev, 1);
                float dg = __shfl_up(prevprev, 1);
                if (t == 0) { up = 0.f; dg = 0.f; }
                int j = d - t - 1;
                float left = prev;
                float x0 = dg * 10.0f;
                float x1 = (g + up) * 10.0f;
                float x2 = (g + left) * 10.0f;
                float mx = fmaxf(x0, fmaxf(x1, x2));
                float lse = mx + __logf(__expf(x0 - mx) + __expf(x1 - mx) + __expf(x2 - mx));
                float val = m + 0.1f * lse;
                float cur = (j >= 1 && j <= 32) ? val : 0.f;
                prevprev = prev;
                prev = cur;
            }
            if (t == 31) ws[WS_FSD + b] = prev;
        }
    }
}

// ============ final combine ============
__device__ float block_reduce(float v, float* red, int t) {
    red[t] = v;
    __syncthreads();
    for (int o = 128; o; o >>= 1) {
        if (t < o) red[t] += red[t + o];
        __syncthreads();
    }
    float r = red[0];
    __syncthreads();
    return r;
}

__global__ __launch_bounds__(256) void final_kernel(
    const float* __restrict__ ai0, const float* __restrict__ ac0,
    const float* __restrict__ ab0, const float* __restrict__ vid0,
    const float* __restrict__ ai1, const float* __restrict__ ac1,
    const float* __restrict__ ab1, const float* __restrict__ vid1,
    const float* __restrict__ ws, float* __restrict__ out) {
    __shared__ float rs0[Bn], rs1[Bn];
    __shared__ float red[256];
    int t = threadIdx.x;
    if (t < Bn) {
        float s0 = 0.f, s1 = 0.f;
        for (int c = 0; c < NCLS; ++c) { s0 += vid0[t * NCLS + c]; s1 += vid1[t * NCLS + c]; }
        rs0[t] = s0;
        rs1[t] = s1;
    }
    __syncthreads();

    float inst0 = 0.f, cont0 = 0.f, back0 = 0.f;
    float inst1 = 0.f, cont1 = 0.f, back1 = 0.f;
    for (int idx = t; idx < Bn * (NCLS + 1); idx += 256) {
        int b = idx / (NCLS + 1), c = idx % (NCLS + 1);
        float v0 = (c < NCLS) ? vid0[b * NCLS + c] : 0.f;
        float v1 = (c < NCLS) ? vid1[b * NCLS + c] : 0.f;
        float wI0 = (c < NCLS) ? (v0 / rs0[b]) : 0.f;
        float wC0 = ((c < NCLS) ? v0 : 1.f) / (rs0[b] + 1.f);
        float wI1 = (c < NCLS) ? (v1 / rs1[b]) : 0.f;
        float wC1 = ((c < NCLS) ? v1 : 1.f) / (rs1[b] + 1.f);
        inst0 += logf(ai0[idx] + 1e-10f) * wI0;
        cont0 += logf(ac0[idx] + 1e-10f) * wC0;
        inst1 += logf(ai1[idx] + 1e-10f) * wI1;
        cont1 += logf(ac1[idx] + 1e-10f) * wC1;
        if (c == NCLS) {
            back0 += logf(ab0[idx] + 1e-10f);
            back1 += logf(ab1[idx] + 1e-10f);
        }
    }
    float sInst0 = block_reduce(inst0, red, t);
    float sCont0 = block_reduce(cont0, red, t);
    float sBack0 = block_reduce(back0, red, t);
    float sInst1 = block_reduce(inst1, red, t);
    float sCont1 = block_reduce(cont1, red, t);
    float sBack1 = block_reduce(back1, red, t);

    float fv0 = 0.f, fv1 = 0.f;
    if (t < Bn) {
        const float* nm = ws + WS_NORM;
        {
            float ni = nm[0 * Bn + t], nc = nm[1 * Bn + t], nb = nm[2 * Bn + t];
            float f1 = fmaxf(50.0f - ni + nc, 0.f);
            float f2 = fmaxf(50.0f - nc + nb, 0.f);
            float f = f1 + f2 + nb;
            fv0 = f * f;
        }
        {
            float ni = nm[3 * Bn + t], nc = nm[4 * Bn + t], nb = nm[5 * Bn + t];
            float f1 = fmaxf(50.0f - ni + nc, 0.f);
            float f2 = fmaxf(50.0f - nc + nb, 0.f);
            float f = f1 + f2 + nb;
            fv1 = f * f;
        }
    }
    float sFeat0 = block_reduce(fv0, red, t) / (float)Bn;
    float sFeat1 = block_reduce(fv1, red, t) / (float)Bn;

    float posL = 0.f, negL = 0.f, posF = 0.f, negF = 0.f, pln = 0.f;
    if (t < Bn) {
        float pl = ws[WS_PAIR + t];
        float lv = ws[WS_LCS + t];
        float fv = ws[WS_FSD + t];
        posL = lv * pl; negL = lv * (1.f - pl);
        posF = fv * pl; negF = fv * (1.f - pl);
        pln = pl;
    }
    float sPosL = block_reduce(posL, red, t);
    float sNegL = block_reduce(negL, red, t);
    float sPosF = block_reduce(posF, red, t);
    float sNegF = block_reduce(negF, red, t);
    float sPln = block_reduce(pln, red, t);

    if (t == 0) {
        float cls0 = -(sInst0 + sCont0 + sBack0) / (float)Bn;
        float cls1 = -(sInst1 + sCont1 + sBack1) / (float)Bn;
        float guide0 = ws[WS_ACC + 0] / (float)Bn;
        float sparse0 = ws[WS_ACC + 1] / (float)(Bn * 2);
        float guide1 = ws[WS_ACC + 2] / (float)Bn;
        float sparse1 = ws[WS_ACC + 3] / (float)(Bn * 2);
        float loss0 = cls0 + 1.0f * guide0 + 5e-05f * sFeat0 + 8e-05f * sparse0;
        float loss1 = cls1 + 1.0f * guide1 + 5e-05f * sFeat1 + 8e-05f * sparse1;
        float acm = 0.5f * (loss0 + loss1);
        float posn = sPln;
        float negn = (float)Bn - posn;
        float lcs_loss = sNegL / (negn + 1e-10f) - sPosL / (posn + 1e-10f);
        float fsd_loss = sNegF / (negn + 1e-10f) - sPosF / (posn + 1e-10f);
        out[0] = acm + 0.01f * lcs_loss + 0.01f * fsd_loss;
    }
}

extern "C" void kernel_launch(void* const* d_in, const int* in_sizes, int n_in,
                              void* d_out, int out_size, void* d_ws, size_t ws_size,
                              hipStream_t stream) {
    (void)in_sizes; (void)n_in; (void)out_size; (void)ws_size;
    const float* ai0  = (const float*)d_in[0];
    const float* ac0  = (const float*)d_in[1];
    const float* ab0  = (const float*)d_in[2];
    const float* vid0 = (const float*)d_in[3];
    const float* att0 = (const float*)d_in[4];
    const float* fi0  = (const float*)d_in[5];
    const float* fc0  = (const float*)d_in[6];
    const float* fb0  = (const float*)d_in[7];
    const float* cas0 = (const float*)d_in[8];
    const float* lcs0 = (const float*)d_in[9];
    const float* fsdA0 = (const float*)d_in[10];
    const float* ai1  = (const float*)d_in[12];
    const float* ac1  = (const float*)d_in[13];
    const float* ab1  = (const float*)d_in[14];
    const float* vid1 = (const float*)d_in[15];
    const float* att1 = (const float*)d_in[16];
    const float* fi1  = (const float*)d_in[17];
    const float* fc1  = (const float*)d_in[18];
    const float* fb1  = (const float*)d_in[19];
    const float* cas1 = (const float*)d_in[20];
    const float* lcs1 = (const float*)d_in[21];
    const float* fsdA1 = (const float*)d_in[22];
    const float* fsdB1 = (const float*)d_in[23];

    float* ws = (float*)d_ws;

    hipMemsetAsync(d_ws, 0, 4 * sizeof(float), stream);  // zero atomic accumulators
    fused_small_kernel<<<609, 256, 0, stream>>>(cas0, att0, cas1, att1,
                                                fi0, fc0, fb0, fi1, fc1, fb1,
                                                vid0, vid1, ws);
    gemm_kernel<<<1024, 256, 0, stream>>>(lcs0, lcs1, fsdA0, fsdA1, fsdB1, ws);
    dp_kernel<<<128, 64, 0, stream>>>(ws);
    final_kernel<<<1, 256, 0, stream>>>(ai0, ac0, ab0, vid0, ai1, ac1, ab1, vid1, ws,
                                        (float*)d_out);
}

// Round 4
// 244.307 us; speedup vs baseline: 4.2369x; 1.1121x over previous
//
#include <hip/hip_runtime.h>
#include <math.h>

#define Bn 64
#define Tn 2048
#define NCLS 20
#define Dn 2048
#define LCSL 64
#define FSDL 32

// ws float offsets (no atomics anywhere; every consumed slot is written each call)
#define WS_LCS 0         // 64   lcs dp results
#define WS_FSD 64        // 64   fsd dp results
#define WS_NORM 128      // 384  feat norms
#define WS_GS 512        // 512  guide/sparse partials [128 blocks][4]
#define WS_LSQ 1024      // 512*128 = 65536  lcs sumsq partials [(b*8+ks)*128 + e]
#define WS_FSQ 66560     // 512*64  = 32768  fsd sumsq partials [((b*2+half)*4+ks)*64 + e]
#define WS_SPART 99328   // 64*8*4096 = 2097152  lcs S partials [(b*8+ks)*4096]
#define WS_MG 2196480    // 64*2*4*1024 = 524288 fsd partials [((b*2+half)*4+ks)*1024]

// ============ mega kernel ============
// blocks 0..511     : LCS partial GEMM (b = bid>>3, ks = bid&7, K=256, KC=32)
// blocks 512..1023  : FSD partial GEMM (b, half, ks; K=256, KC=64)
// blocks 1024..1151 : guide+sparse partial reductions
// blocks 1152..1247 : feature norms (384 rows, wave per row)
__global__ __launch_bounds__(256) void mega_kernel(
    const float* __restrict__ lcs0, const float* __restrict__ lcs1,
    const float* __restrict__ fA0, const float* __restrict__ fA1,
    const float* __restrict__ fB1,
    const float* __restrict__ vid0, const float* __restrict__ vid1,
    const float* __restrict__ cas0, const float* __restrict__ att0,
    const float* __restrict__ cas1, const float* __restrict__ att1,
    const float* __restrict__ f0, const float* __restrict__ f1,
    const float* __restrict__ f2, const float* __restrict__ f3,
    const float* __restrict__ f4, const float* __restrict__ f5,
    float* __restrict__ ws) {
    __shared__ float tA[2176];   // LCS: [k<32][row<64] stride 68 | FSD: [k<64][row<32] stride 34
    __shared__ float tB[2176];
    const int t = threadIdx.x;
    const int bid = blockIdx.x;

    if (bid < 512) {
        // -------- LCS partial GEMM --------
        const int b = bid >> 3, ks = bid & 7;
        const float* c0 = lcs0 + (size_t)b * LCSL * Dn + ks * 256;
        const float* c1 = lcs1 + (size_t)b * LCSL * Dn + ks * 256;
        const int ti = t >> 4, tj = t & 15;
        const int i0 = ti * 4, j0 = tj * 4;
        float acc[4][4] = {};
        float sqa0 = 0.f, sqa1 = 0.f, sqb0 = 0.f, sqb1 = 0.f;

        for (int kc = 0; kc < 256; kc += 32) {
            __syncthreads();
            #pragma unroll
            for (int l = 0; l < 2; ++l) {
                int idx4 = l * 256 + t;        // 512 float4 slots = 64 rows x 8
                int row = idx4 >> 3;
                int kq = (idx4 & 7) * 4;       // 0..28
                float4 av = *(const float4*)(c0 + (size_t)row * Dn + kc + kq);
                float4 bv = *(const float4*)(c1 + (size_t)row * Dn + kc + kq);
                int rowx = row ^ kq;           // swizzle s(k)=k&28 == kq here
                tA[(kq + 0) * 68 + rowx] = av.x;
                tA[(kq + 1) * 68 + rowx] = av.y;
                tA[(kq + 2) * 68 + rowx] = av.z;
                tA[(kq + 3) * 68 + rowx] = av.w;
                tB[(kq + 0) * 68 + rowx] = bv.x;
                tB[(kq + 1) * 68 + rowx] = bv.y;
                tB[(kq + 2) * 68 + rowx] = bv.z;
                tB[(kq + 3) * 68 + rowx] = bv.w;
                float sa = av.x * av.x + av.y * av.y + av.z * av.z + av.w * av.w;
                float sb = bv.x * bv.x + bv.y * bv.y + bv.z * bv.z + bv.w * bv.w;
                if (l == 0) { sqa0 += sa; sqb0 += sb; }
                else        { sqa1 += sa; sqb1 += sb; }
            }
            __syncthreads();
            #pragma unroll 8
            for (int k = 0; k < 32; ++k) {
                int sk = k & 28;
                float4 a4 = *(const float4*)&tA[k * 68 + (i0 ^ sk)];
                float4 b4 = *(const float4*)&tB[k * 68 + (j0 ^ sk)];
                float a[4] = {a4.x, a4.y, a4.z, a4.w};
                float bb[4] = {b4.x, b4.y, b4.z, b4.w};
                #pragma unroll
                for (int r = 0; r < 4; ++r)
                    #pragma unroll
                    for (int c = 0; c < 4; ++c)
                        acc[r][c] = fmaf(a[r], bb[c], acc[r][c]);
            }
        }
        float* dst = ws + WS_SPART + (size_t)(b * 8 + ks) * 4096;
        #pragma unroll
        for (int r = 0; r < 4; ++r) {
            float4 v = {acc[r][0], acc[r][1], acc[r][2], acc[r][3]};
            *(float4*)(dst + (i0 + r) * 64 + j0) = v;
        }
        // sumsq: thread t owns rows r0=t>>3 (l=0) and r0+32 (l=1); 8 lanes share a row
        #pragma unroll
        for (int m = 1; m < 8; m <<= 1) {
            sqa0 += __shfl_xor(sqa0, m);
            sqa1 += __shfl_xor(sqa1, m);
            sqb0 += __shfl_xor(sqb0, m);
            sqb1 += __shfl_xor(sqb1, m);
        }
        if ((t & 7) == 0) {
            int r0 = t >> 3;
            float* q = ws + WS_LSQ + (size_t)(b * 8 + ks) * 128;
            q[r0] = sqa0;
            q[r0 + 32] = sqa1;
            q[64 + r0] = sqb0;
            q[96 + r0] = sqb1;
        }
    } else if (bid < 1024) {
        // -------- FSD partial GEMM --------
        const int q = bid - 512;
        const int b = q >> 3, half = (q >> 2) & 1, ks = q & 3;
        float ps = 0.f;
        for (int c = 0; c < NCLS; ++c) ps += vid0[b * NCLS + c] * vid1[b * NCLS + c];
        const float* base1 = (ps > 0.f) ? fA1 : fB1;
        const float* c0 = fA0 + (size_t)b * FSDL * Dn + half * 1024 + ks * 256;
        const float* c1 = base1 + (size_t)b * FSDL * Dn + half * 1024 + ks * 256;
        const int ti = t >> 4, tj = t & 15;
        const int i0 = ti * 2, j0 = tj * 2;
        float acc[2][2] = {};
        float sqa0 = 0.f, sqa1 = 0.f, sqb0 = 0.f, sqb1 = 0.f;

        for (int kc = 0; kc < 256; kc += 64) {
            __syncthreads();
            #pragma unroll
            for (int l = 0; l < 2; ++l) {
                int idx4 = l * 256 + t;        // 512 float4 slots = 32 rows x 16
                int row = idx4 >> 4;
                int kq = (idx4 & 15) * 4;      // 0..60
                float4 av = *(const float4*)(c0 + (size_t)row * Dn + kc + kq);
                float4 bv = *(const float4*)(c1 + (size_t)row * Dn + kc + kq);
                {
                    int r0x = row ^ ((kq + 0) & 30);
                    int r1x = row ^ ((kq + 1) & 30);
                    int r2x = row ^ ((kq + 2) & 30);
                    int r3x = row ^ ((kq + 3) & 30);
                    tA[(kq + 0) * 34 + r0x] = av.x;
                    tA[(kq + 1) * 34 + r1x] = av.y;
                    tA[(kq + 2) * 34 + r2x] = av.z;
                    tA[(kq + 3) * 34 + r3x] = av.w;
                    tB[(kq + 0) * 34 + r0x] = bv.x;
                    tB[(kq + 1) * 34 + r1x] = bv.y;
                    tB[(kq + 2) * 34 + r2x] = bv.z;
                    tB[(kq + 3) * 34 + r3x] = bv.w;
                }
                float sa = av.x * av.x + av.y * av.y + av.z * av.z + av.w * av.w;
                float sb = bv.x * bv.x + bv.y * bv.y + bv.z * bv.z + bv.w * bv.w;
                if (l == 0) { sqa0 += sa; sqb0 += sb; }
                else        { sqa1 += sa; sqb1 += sb; }
            }
            __syncthreads();
            #pragma unroll 8
            for (int k = 0; k < 64; ++k) {
                int sk = k & 30;
                float2 a2 = *(const float2*)&tA[k * 34 + (i0 ^ sk)];
                float2 b2 = *(const float2*)&tB[k * 34 + (j0 ^ sk)];
                acc[0][0] = fmaf(a2.x, b2.x, acc[0][0]);
                acc[0][1] = fmaf(a2.x, b2.y, acc[0][1]);
                acc[1][0] = fmaf(a2.y, b2.x, acc[1][0]);
                acc[1][1] = fmaf(a2.y, b2.y, acc[1][1]);
            }
        }
        float* dst = ws + WS_MG + (size_t)((b * 2 + half) * 4 + ks) * 1024;
        #pragma unroll
        for (int r = 0; r < 2; ++r) {
            float2 v = {acc[r][0], acc[r][1]};
            *(float2*)(dst + (i0 + r) * 32 + j0) = v;
        }
        // sumsq: thread t owns rows r0=t>>4 (l=0) and r0+16 (l=1); 16 lanes share a row
        #pragma unroll
        for (int m = 1; m < 16; m <<= 1) {
            sqa0 += __shfl_xor(sqa0, m);
            sqa1 += __shfl_xor(sqa1, m);
            sqb0 += __shfl_xor(sqb0, m);
            sqb1 += __shfl_xor(sqb1, m);
        }
        if ((t & 15) == 0) {
            int r0 = t >> 4;
            float* qq = ws + WS_FSQ + (size_t)((b * 2 + half) * 4 + ks) * 64;
            qq[r0] = sqa0;
            qq[r0 + 16] = sqa1;
            qq[32 + r0] = sqb0;
            qq[48 + r0] = sqb1;
        }
    } else if (bid < 1152) {
        // -------- guide + sparse partials (no atomics) --------
        const int gb = bid - 1024;
        const int N = Bn * Tn;
        float g0 = 0.f, s0 = 0.f, g1 = 0.f, s1 = 0.f;
        for (int n = gb * 256 + t; n < 2 * N; n += 128 * 256) {
            int sfx = (n >= N);
            int m = sfx ? (n - N) : n;
            const float* cas = sfx ? cas1 : cas0;
            const float* att = sfx ? att1 : att0;
            float a0 = att[m * 3 + 0];
            float a1 = att[m * 3 + 1];
            float g = fabsf(1.0f - cas[m * (NCLS + 1) + NCLS] - a0);
            float s = a0 + a1;
            if (sfx) { g1 += g; s1 += s; } else { g0 += g; s0 += s; }
        }
        float vals[4] = {g0, s0, g1, s1};
        #pragma unroll
        for (int v = 0; v < 4; ++v) tA[v * 256 + t] = vals[v];
        __syncthreads();
        for (int o = 128; o; o >>= 1) {
            if (t < o) {
                #pragma unroll
                for (int v = 0; v < 4; ++v) tA[v * 256 + t] += tA[v * 256 + t + o];
            }
            __syncthreads();
        }
        if (t < 4) ws[WS_GS + gb * 4 + t] = tA[t * 256];
    } else {
        // -------- feature norms: 384 rows, wave per row --------
        int R = (bid - 1152) * 4 + (t >> 6);
        int lane = t & 63;
        const float* arr[6] = {f0, f1, f2, f3, f4, f5};
        const float* p = arr[R >> 6] + (size_t)(R & 63) * Dn;
        float s = 0.f;
        #pragma unroll
        for (int qd = 0; qd < 8; ++qd) {
            float4 v = *(const float4*)(p + qd * 256 + lane * 4);
            s += v.x * v.x + v.y * v.y + v.z * v.z + v.w * v.w;
        }
        for (int off = 32; off; off >>= 1) s += __shfl_down(s, off);
        if (lane == 0) ws[WS_NORM + R] = sqrtf(s);
    }
}

// ============ dp kernel: LCS (0..63) + FSD (64..127), 256 threads ============
__global__ __launch_bounds__(256) void dp_kernel(float* __restrict__ ws) {
    const int t = threadIdx.x;
    if (blockIdx.x < 64) {
        const int b = blockIdx.x;
        __shared__ float S[64 * 68];
        __shared__ float inv[128];
        if (t < 128) {
            float s = 0.f;
            #pragma unroll
            for (int ks = 0; ks < 8; ++ks)
                s += ws[WS_LSQ + (size_t)(b * 8 + ks) * 128 + t];
            inv[t] = 1.0f / sqrtf(s);
        }
        __syncthreads();
        const float* sp = ws + WS_SPART + (size_t)b * 32768;
        #pragma unroll
        for (int qd = 0; qd < 4; ++qd) {
            int idx4 = qd * 256 + t;           // 1024 float4 slots
            int i = idx4 >> 4, j = (idx4 & 15) * 4;
            float4 v = {0.f, 0.f, 0.f, 0.f};
            #pragma unroll
            for (int ks = 0; ks < 8; ++ks) {
                float4 p = *(const float4*)(sp + (size_t)ks * 4096 + idx4 * 4);
                v.x += p.x; v.y += p.y; v.z += p.z; v.w += p.w;
            }
            float ri = inv[i];
            S[i * 68 + j + 0] = v.x * ri * inv[64 + j + 0];
            S[i * 68 + j + 1] = v.y * ri * inv[64 + j + 1];
            S[i * 68 + j + 2] = v.z * ri * inv[64 + j + 2];
            S[i * 68 + j + 3] = v.w * ri * inv[64 + j + 3];
        }
        __syncthreads();
        if (t < 64) {
            float prev = 0.f, prevprev = 0.f;
            float sval_next = S[t * 68 + 0];
            for (int d = 2; d <= 128; ++d) {
                float s = sval_next;
                int jn = d - t - 1;
                if (jn >= 0 && jn < 64) sval_next = S[t * 68 + jn];
                float up = __shfl_up(prev, 1);
                float dg = __shfl_up(prevprev, 1);
                if (t == 0) { up = 0.f; dg = 0.f; }
                int j = d - t - 1;
                float left = prev;
                float val = (s > 0.5f) ? (dg + s) : fmaxf(up, left);
                float cur = (j >= 1 && j <= 64) ? val : 0.f;
                prevprev = prev;
                prev = cur;
            }
            if (t == 63) ws[WS_LCS + b] = prev;
        }
    } else {
        const int b = blockIdx.x - 64;
        __shared__ float M[32 * 36], G[32 * 36];
        __shared__ float inv[128];
        if (t < 128) {
            int half = t >> 6, sub = t & 63;
            float s = 0.f;
            #pragma unroll
            for (int ks = 0; ks < 4; ++ks)
                s += ws[WS_FSQ + (size_t)((b * 2 + half) * 4 + ks) * 64 + sub];
            inv[t] = 1.0f / sqrtf(s);
        }
        __syncthreads();
        {
            int idx4 = t;                      // 256 float4 slots = 1024 floats
            int i = idx4 >> 3, j = (idx4 & 7) * 4;
            float4 vM = {0.f, 0.f, 0.f, 0.f}, vG = {0.f, 0.f, 0.f, 0.f};
            #pragma unroll
            for (int ks = 0; ks < 4; ++ks) {
                float4 pM = *(const float4*)(ws + WS_MG + (size_t)((b * 2 + 0) * 4 + ks) * 1024 + idx4 * 4);
                float4 pG = *(const float4*)(ws + WS_MG + (size_t)((b * 2 + 1) * 4 + ks) * 1024 + idx4 * 4);
                vM.x += pM.x; vM.y += pM.y; vM.z += pM.z; vM.w += pM.w;
                vG.x += pG.x; vG.y += pG.y; vG.z += pG.z; vG.w += pG.w;
            }
            float riM = inv[i], riG = inv[64 + i];
            M[i * 36 + j + 0] = vM.x * riM * inv[32 + j + 0];
            M[i * 36 + j + 1] = vM.y * riM * inv[32 + j + 1];
            M[i * 36 + j + 2] = vM.z * riM * inv[32 + j + 2];
            M[i * 36 + j + 3] = vM.w * riM * inv[32 + j + 3];
            G[i * 36 + j + 0] = vG.x * riG * inv[96 + j + 0];
            G[i * 36 + j + 1] = vG.y * riG * inv[96 + j + 1];
            G[i * 36 + j + 2] = vG.z * riG * inv[96 + j + 2];
            G[i * 36 + j + 3] = vG.w * riG * inv[96 + j + 3];
        }
        __syncthreads();
        if (t < 32) {
            float prev = 0.f, prevprev = 0.f;
            float m_next = M[t * 36 + 0], g_next = G[t * 36 + 0];
            for (int d = 2; d <= 64; ++d) {
                float m = m_next, g = g_next;
                int jn = d - t - 1;
                if (jn >= 0 && jn < 32) { m_next = M[t * 36 + jn]; g_next = G[t * 36 + jn]; }
                float up = __shfl_up(prev, 1);
                float dg = __shfl_up(prevprev, 1);
                if (t == 0) { up = 0.f; dg = 0.f; }
                int j = d - t - 1;
                float left = prev;
                float x0 = dg * 10.0f;
                float x1 = (g + up) * 10.0f;
                float x2 = (g + left) * 10.0f;
                float mx = fmaxf(x0, fmaxf(x1, x2));
                float lse = mx + __logf(__expf(x0 - mx) + __expf(x1 - mx) + __expf(x2 - mx));
                float val = m + 0.1f * lse;
                float cur = (j >= 1 && j <= 32) ? val : 0.f;
                prevprev = prev;
                prev = cur;
            }
            if (t == 31) ws[WS_FSD + b] = prev;
        }
    }
}

// ============ final combine ============
__device__ float block_reduce(float v, float* red, int t) {
    red[t] = v;
    __syncthreads();
    for (int o = 128; o; o >>= 1) {
        if (t < o) red[t] += red[t + o];
        __syncthreads();
    }
    float r = red[0];
    __syncthreads();
    return r;
}

__global__ __launch_bounds__(256) void final_kernel(
    const float* __restrict__ ai0, const float* __restrict__ ac0,
    const float* __restrict__ ab0, const float* __restrict__ vid0,
    const float* __restrict__ ai1, const float* __restrict__ ac1,
    const float* __restrict__ ab1, const float* __restrict__ vid1,
    const float* __restrict__ ws, float* __restrict__ out) {
    __shared__ float rs0[Bn], rs1[Bn], plsh[Bn];
    __shared__ float red[256];
    int t = threadIdx.x;
    if (t < Bn) {
        float s0 = 0.f, s1 = 0.f, pp = 0.f;
        for (int c = 0; c < NCLS; ++c) {
            float a = vid0[t * NCLS + c], bl = vid1[t * NCLS + c];
            s0 += a; s1 += bl; pp += a * bl;
        }
        rs0[t] = s0;
        rs1[t] = s1;
        plsh[t] = (pp > 0.f) ? 1.f : 0.f;
    }
    __syncthreads();

    float inst0 = 0.f, cont0 = 0.f, back0 = 0.f;
    float inst1 = 0.f, cont1 = 0.f, back1 = 0.f;
    for (int idx = t; idx < Bn * (NCLS + 1); idx += 256) {
        int b = idx / (NCLS + 1), c = idx % (NCLS + 1);
        float v0 = (c < NCLS) ? vid0[b * NCLS + c] : 0.f;
        float v1 = (c < NCLS) ? vid1[b * NCLS + c] : 0.f;
        float wI0 = (c < NCLS) ? (v0 / rs0[b]) : 0.f;
        float wC0 = ((c < NCLS) ? v0 : 1.f) / (rs0[b] + 1.f);
        float wI1 = (c < NCLS) ? (v1 / rs1[b]) : 0.f;
        float wC1 = ((c < NCLS) ? v1 : 1.f) / (rs1[b] + 1.f);
        inst0 += logf(ai0[idx] + 1e-10f) * wI0;
        cont0 += logf(ac0[idx] + 1e-10f) * wC0;
        inst1 += logf(ai1[idx] + 1e-10f) * wI1;
        cont1 += logf(ac1[idx] + 1e-10f) * wC1;
        if (c == NCLS) {
            back0 += logf(ab0[idx] + 1e-10f);
            back1 += logf(ab1[idx] + 1e-10f);
        }
    }
    float sInst0 = block_reduce(inst0, red, t);
    float sCont0 = block_reduce(cont0, red, t);
    float sBack0 = block_reduce(back0, red, t);
    float sInst1 = block_reduce(inst1, red, t);
    float sCont1 = block_reduce(cont1, red, t);
    float sBack1 = block_reduce(back1, red, t);

    // guide/sparse partials
    float g0 = 0.f, s0v = 0.f, g1 = 0.f, s1v = 0.f;
    for (int i = t; i < 128; i += 256) {
        g0  += ws[WS_GS + i * 4 + 0];
        s0v += ws[WS_GS + i * 4 + 1];
        g1  += ws[WS_GS + i * 4 + 2];
        s1v += ws[WS_GS + i * 4 + 3];
    }
    float sG0 = block_reduce(g0, red, t);
    float sS0 = block_reduce(s0v, red, t);
    float sG1 = block_reduce(g1, red, t);
    float sS1 = block_reduce(s1v, red, t);

    float fv0 = 0.f, fv1 = 0.f;
    if (t < Bn) {
        const float* nm = ws + WS_NORM;
        {
            float ni = nm[0 * Bn + t], nc = nm[1 * Bn + t], nb = nm[2 * Bn + t];
            float f1 = fmaxf(50.0f - ni + nc, 0.f);
            float f2 = fmaxf(50.0f - nc + nb, 0.f);
            float f = f1 + f2 + nb;
            fv0 = f * f;
        }
        {
            float ni = nm[3 * Bn + t], nc = nm[4 * Bn + t], nb = nm[5 * Bn + t];
            float f1 = fmaxf(50.0f - ni + nc, 0.f);
            float f2 = fmaxf(50.0f - nc + nb, 0.f);
            float f = f1 + f2 + nb;
            fv1 = f * f;
        }
    }
    float sFeat0 = block_reduce(fv0, red, t) / (float)Bn;
    float sFeat1 = block_reduce(fv1, red, t) / (float)Bn;

    float posL = 0.f, negL = 0.f, posF = 0.f, negF = 0.f, pln = 0.f;
    if (t < Bn) {
        float pl = plsh[t];
        float lv = ws[WS_LCS + t];
        float fv = ws[WS_FSD + t];
        posL = lv * pl; negL = lv * (1.f - pl);
        posF = fv * pl; negF = fv * (1.f - pl);
        pln = pl;
    }
    float sPosL = block_reduce(posL, red, t);
    float sNegL = block_reduce(negL, red, t);
    float sPosF = block_reduce(posF, red, t);
    float sNegF = block_reduce(negF, red, t);
    float sPln = block_reduce(pln, red, t);

    if (t == 0) {
        float cls0 = -(sInst0 + sCont0 + sBack0) / (float)Bn;
        float cls1 = -(sInst1 + sCont1 + sBack1) / (float)Bn;
        float guide0 = sG0 / (float)Bn;
        float sparse0 = sS0 / (float)(Bn * 2);
        float guide1 = sG1 / (float)Bn;
        float sparse1 = sS1 / (float)(Bn * 2);
        float loss0 = cls0 + 1.0f * guide0 + 5e-05f * sFeat0 + 8e-05f * sparse0;
        float loss1 = cls1 + 1.0f * guide1 + 5e-05f * sFeat1 + 8e-05f * sparse1;
        float acm = 0.5f * (loss0 + loss1);
        float posn = sPln;
        float negn = (float)Bn - posn;
        float lcs_loss = sNegL / (negn + 1e-10f) - sPosL / (posn + 1e-10f);
        float fsd_loss = sNegF / (negn + 1e-10f) - sPosF / (posn + 1e-10f);
        out[0] = acm + 0.01f * lcs_loss + 0.01f * fsd_loss;
    }
}

extern "C" void kernel_launch(void* const* d_in, const int* in_sizes, int n_in,
                              void* d_out, int out_size, void* d_ws, size_t ws_size,
                              hipStream_t stream) {
    (void)in_sizes; (void)n_in; (void)out_size; (void)ws_size;
    const float* ai0  = (const float*)d_in[0];
    const float* ac0  = (const float*)d_in[1];
    const float* ab0  = (const float*)d_in[2];
    const float* vid0 = (const float*)d_in[3];
    const float* att0 = (const float*)d_in[4];
    const float* fi0  = (const float*)d_in[5];
    const float* fc0  = (const float*)d_in[6];
    const float* fb0  = (const float*)d_in[7];
    const float* cas0 = (const float*)d_in[8];
    const float* lcs0 = (const float*)d_in[9];
    const float* fsdA0 = (const float*)d_in[10];
    const float* ai1  = (const float*)d_in[12];
    const float* ac1  = (const float*)d_in[13];
    const float* ab1  = (const float*)d_in[14];
    const float* vid1 = (const float*)d_in[15];
    const float* att1 = (const float*)d_in[16];
    const float* fi1  = (const float*)d_in[17];
    const float* fc1  = (const float*)d_in[18];
    const float* fb1  = (const float*)d_in[19];
    const float* cas1 = (const float*)d_in[20];
    const float* lcs1 = (const float*)d_in[21];
    const float* fsdA1 = (const float*)d_in[22];
    const float* fsdB1 = (const float*)d_in[23];

    float* ws = (float*)d_ws;

    mega_kernel<<<1248, 256, 0, stream>>>(lcs0, lcs1, fsdA0, fsdA1, fsdB1,
                                          vid0, vid1, cas0, att0, cas1, att1,
                                          fi0, fc0, fb0, fi1, fc1, fb1, ws);
    dp_kernel<<<128, 256, 0, stream>>>(ws);
    final_kernel<<<1, 256, 0, stream>>>(ai0, ac0, ab0, vid0, ai1, ac1, ab1, vid1, ws,
                                        (float*)d_out);
}

// Round 5
// 240.553 us; speedup vs baseline: 4.3030x; 1.0156x over previous
//
#include <hip/hip_runtime.h>
#include <math.h>

#define Bn 64
#define Tn 2048
#define NCLS 20
#define Dn 2048
#define LCSL 64
#define FSDL 32

typedef __bf16 bf16x4 __attribute__((ext_vector_type(4)));
typedef __bf16 bf16x8 __attribute__((ext_vector_type(8)));
typedef float f32x4 __attribute__((ext_vector_type(4)));

// ws float offsets (no atomics; every consumed slot written each call)
#define WS_LCS 0         // 64   lcs dp results
#define WS_FSD 64        // 64   fsd dp results
#define WS_NORM 128      // 384  feat norms
#define WS_GS 512        // 512  guide/sparse partials [128 blocks][4]
#define WS_LSQ 1024      // 512*128 lcs sumsq partials [(b*8+ks)*128 + e]
#define WS_FSQ 66560     // 512*64  fsd sumsq partials [((b*2+half)*4+ks)*64 + e]
#define WS_SPART 99328   // 64*8*4096 lcs S partials [(b*8+ks)*4096]
#define WS_MG 2196480    // 64*2*4*1024 fsd partials [((b*2+half)*4+ks)*1024]

// ============ mega kernel ============
// blocks 0..511     : LCS partial GEMM via MFMA (b=bid>>3, ks=bid&7, K=256)
// blocks 512..1023  : FSD partial GEMM via MFMA (b, half, ks; K=256)
// blocks 1024..1151 : guide+sparse partial reductions
// blocks 1152..1247 : feature norms (384 rows, wave per row)
__global__ __launch_bounds__(256) void mega_kernel(
    const float* __restrict__ lcs0, const float* __restrict__ lcs1,
    const float* __restrict__ fA0, const float* __restrict__ fA1,
    const float* __restrict__ fB1,
    const float* __restrict__ vid0, const float* __restrict__ vid1,
    const float* __restrict__ cas0, const float* __restrict__ att0,
    const float* __restrict__ cas1, const float* __restrict__ att1,
    const float* __restrict__ f0, const float* __restrict__ f1,
    const float* __restrict__ f2, const float* __restrict__ f3,
    const float* __restrict__ f4, const float* __restrict__ f5,
    float* __restrict__ ws) {
    __shared__ __bf16 tA[4096];   // LCS: [row<64][k<64] (8B-chunk XOR swizzle) | FSD: [row<32][k<64]
    __shared__ __bf16 tB[4096];
    const int t = threadIdx.x;
    const int bid = blockIdx.x;
    const int w = t >> 6, lane = t & 63;
    const int quad = lane >> 4, l16 = lane & 15;

    if (bid < 512) {
        // -------- LCS partial GEMM (MFMA): out 64x64, K=256, kc=64 --------
        const int b = bid >> 3, ks = bid & 7;
        const float* c0 = lcs0 + (size_t)b * LCSL * Dn + ks * 256;
        const float* c1 = lcs1 + (size_t)b * LCSL * Dn + ks * 256;

        f32x4 acc[4] = {};
        float sqa[4] = {0.f, 0.f, 0.f, 0.f}, sqb[4] = {0.f, 0.f, 0.f, 0.f};
        float4 pA[4], pB[4];
        #pragma unroll
        for (int l = 0; l < 4; ++l) {
            int idx4 = l * 256 + t;            // 1024 slots = 64 rows x 16 float4
            int row = idx4 >> 4, kq4 = idx4 & 15;
            pA[l] = *(const float4*)(c0 + (size_t)row * Dn + kq4 * 4);
            pB[l] = *(const float4*)(c1 + (size_t)row * Dn + kq4 * 4);
        }
        for (int kc = 0; kc < 4; ++kc) {
            __syncthreads();
            #pragma unroll
            for (int l = 0; l < 4; ++l) {
                int idx4 = l * 256 + t;
                int row = idx4 >> 4, kq4 = idx4 & 15;
                int c = kq4 >> 1, h = kq4 & 1;
                int pos = row * 64 + ((c ^ (row & 7)) << 3) + h * 4;
                float4 av = pA[l], bv = pB[l];
                bf16x4 a4 = {(__bf16)av.x, (__bf16)av.y, (__bf16)av.z, (__bf16)av.w};
                bf16x4 b4 = {(__bf16)bv.x, (__bf16)bv.y, (__bf16)bv.z, (__bf16)bv.w};
                *(bf16x4*)&tA[pos] = a4;
                *(bf16x4*)&tB[pos] = b4;
                sqa[l] += av.x * av.x + av.y * av.y + av.z * av.z + av.w * av.w;
                sqb[l] += bv.x * bv.x + bv.y * bv.y + bv.z * bv.z + bv.w * bv.w;
            }
            if (kc < 3) {
                const float* n0 = c0 + (kc + 1) * 64;
                const float* n1 = c1 + (kc + 1) * 64;
                #pragma unroll
                for (int l = 0; l < 4; ++l) {
                    int idx4 = l * 256 + t;
                    int row = idx4 >> 4, kq4 = idx4 & 15;
                    pA[l] = *(const float4*)(n0 + (size_t)row * Dn + kq4 * 4);
                    pB[l] = *(const float4*)(n1 + (size_t)row * Dn + kq4 * 4);
                }
            }
            __syncthreads();
            #pragma unroll
            for (int s = 0; s < 2; ++s) {
                int ar = w * 16 + l16;
                int ac_ = (s * 4 + quad) ^ (ar & 7);
                bf16x8 af = *(const bf16x8*)&tA[ar * 64 + (ac_ << 3)];
                #pragma unroll
                for (int tj = 0; tj < 4; ++tj) {
                    int br = tj * 16 + l16;
                    int bc = (s * 4 + quad) ^ (br & 7);
                    bf16x8 bf = *(const bf16x8*)&tB[br * 64 + (bc << 3)];
                    acc[tj] = __builtin_amdgcn_mfma_f32_16x16x32_bf16(af, bf, acc[tj], 0, 0, 0);
                }
            }
        }
        // write partial S (f32)
        float* dst = ws + WS_SPART + (size_t)(b * 8 + ks) * 4096;
        #pragma unroll
        for (int tj = 0; tj < 4; ++tj)
            #pragma unroll
            for (int rg = 0; rg < 4; ++rg)
                dst[(w * 16 + quad * 4 + rg) * 64 + tj * 16 + l16] = acc[tj][rg];
        // sumsq partials: iteration l covers rows l*16 + (t>>4); 16 lanes share a row
        #pragma unroll
        for (int l = 0; l < 4; ++l) {
            float sa = sqa[l], sb = sqb[l];
            #pragma unroll
            for (int m = 1; m < 16; m <<= 1) {
                sa += __shfl_xor(sa, m);
                sb += __shfl_xor(sb, m);
            }
            if ((t & 15) == 0) {
                int r = l * 16 + (t >> 4);
                float* q = ws + WS_LSQ + (size_t)(b * 8 + ks) * 128;
                q[r] = sa;
                q[64 + r] = sb;
            }
        }
    } else if (bid < 1024) {
        // -------- FSD partial GEMM (MFMA): out 32x32, K=256, kc=64 --------
        const int qb = bid - 512;
        const int b = qb >> 3, half = (qb >> 2) & 1, ks = qb & 3;
        float ps = 0.f;
        for (int c = 0; c < NCLS; ++c) ps += vid0[b * NCLS + c] * vid1[b * NCLS + c];
        const float* base1 = (ps > 0.f) ? fA1 : fB1;
        const float* c0 = fA0 + (size_t)b * FSDL * Dn + half * 1024 + ks * 256;
        const float* c1 = base1 + (size_t)b * FSDL * Dn + half * 1024 + ks * 256;
        const int wi = w >> 1, wj = w & 1;

        f32x4 acc = {};
        float sqa[2] = {0.f, 0.f}, sqb[2] = {0.f, 0.f};
        float4 pA[2], pB[2];
        #pragma unroll
        for (int l = 0; l < 2; ++l) {
            int idx4 = l * 256 + t;            // 512 slots = 32 rows x 16 float4
            int row = idx4 >> 4, kq4 = idx4 & 15;
            pA[l] = *(const float4*)(c0 + (size_t)row * Dn + kq4 * 4);
            pB[l] = *(const float4*)(c1 + (size_t)row * Dn + kq4 * 4);
        }
        for (int kc = 0; kc < 4; ++kc) {
            __syncthreads();
            #pragma unroll
            for (int l = 0; l < 2; ++l) {
                int idx4 = l * 256 + t;
                int row = idx4 >> 4, kq4 = idx4 & 15;
                int c = kq4 >> 1, h = kq4 & 1;
                int pos = row * 64 + ((c ^ (row & 7)) << 3) + h * 4;
                float4 av = pA[l], bv = pB[l];
                bf16x4 a4 = {(__bf16)av.x, (__bf16)av.y, (__bf16)av.z, (__bf16)av.w};
                bf16x4 b4 = {(__bf16)bv.x, (__bf16)bv.y, (__bf16)bv.z, (__bf16)bv.w};
                *(bf16x4*)&tA[pos] = a4;
                *(bf16x4*)&tB[pos] = b4;
                sqa[l] += av.x * av.x + av.y * av.y + av.z * av.z + av.w * av.w;
                sqb[l] += bv.x * bv.x + bv.y * bv.y + bv.z * bv.z + bv.w * bv.w;
            }
            if (kc < 3) {
                const float* n0 = c0 + (kc + 1) * 64;
                const float* n1 = c1 + (kc + 1) * 64;
                #pragma unroll
                for (int l = 0; l < 2; ++l) {
                    int idx4 = l * 256 + t;
                    int row = idx4 >> 4, kq4 = idx4 & 15;
                    pA[l] = *(const float4*)(n0 + (size_t)row * Dn + kq4 * 4);
                    pB[l] = *(const float4*)(n1 + (size_t)row * Dn + kq4 * 4);
                }
            }
            __syncthreads();
            #pragma unroll
            for (int s = 0; s < 2; ++s) {
                int ar = wi * 16 + l16;
                int ac_ = (s * 4 + quad) ^ (ar & 7);
                bf16x8 af = *(const bf16x8*)&tA[ar * 64 + (ac_ << 3)];
                int br = wj * 16 + l16;
                int bc = (s * 4 + quad) ^ (br & 7);
                bf16x8 bf = *(const bf16x8*)&tB[br * 64 + (bc << 3)];
                acc = __builtin_amdgcn_mfma_f32_16x16x32_bf16(af, bf, acc, 0, 0, 0);
            }
        }
        float* dst = ws + WS_MG + (size_t)((b * 2 + half) * 4 + ks) * 1024;
        #pragma unroll
        for (int rg = 0; rg < 4; ++rg)
            dst[(wi * 16 + quad * 4 + rg) * 32 + wj * 16 + l16] = acc[rg];
        #pragma unroll
        for (int l = 0; l < 2; ++l) {
            float sa = sqa[l], sb = sqb[l];
            #pragma unroll
            for (int m = 1; m < 16; m <<= 1) {
                sa += __shfl_xor(sa, m);
                sb += __shfl_xor(sb, m);
            }
            if ((t & 15) == 0) {
                int r = l * 16 + (t >> 4);
                float* qq = ws + WS_FSQ + (size_t)((b * 2 + half) * 4 + ks) * 64;
                qq[r] = sa;
                qq[32 + r] = sb;
            }
        }
    } else if (bid < 1152) {
        // -------- guide + sparse partials --------
        const int gb = bid - 1024;
        const int N = Bn * Tn;
        float g0 = 0.f, s0 = 0.f, g1 = 0.f, s1 = 0.f;
        for (int n = gb * 256 + t; n < 2 * N; n += 128 * 256) {
            int sfx = (n >= N);
            int m = sfx ? (n - N) : n;
            const float* cas = sfx ? cas1 : cas0;
            const float* att = sfx ? att1 : att0;
            float a0 = att[m * 3 + 0];
            float a1 = att[m * 3 + 1];
            float g = fabsf(1.0f - cas[m * (NCLS + 1) + NCLS] - a0);
            float s = a0 + a1;
            if (sfx) { g1 += g; s1 += s; } else { g0 += g; s0 += s; }
        }
        float* red = (float*)tA;  // 4 KB of the 8 KB tile
        float vals[4] = {g0, s0, g1, s1};
        #pragma unroll
        for (int v = 0; v < 4; ++v) red[v * 256 + t] = vals[v];
        __syncthreads();
        for (int o = 128; o; o >>= 1) {
            if (t < o) {
                #pragma unroll
                for (int v = 0; v < 4; ++v) red[v * 256 + t] += red[v * 256 + t + o];
            }
            __syncthreads();
        }
        if (t < 4) ws[WS_GS + gb * 4 + t] = red[t * 256];
    } else {
        // -------- feature norms: 384 rows, wave per row --------
        int R = (bid - 1152) * 4 + w;
        const float* arr[6] = {f0, f1, f2, f3, f4, f5};
        const float* p = arr[R >> 6] + (size_t)(R & 63) * Dn;
        float s = 0.f;
        #pragma unroll
        for (int qd = 0; qd < 8; ++qd) {
            float4 v = *(const float4*)(p + qd * 256 + lane * 4);
            s += v.x * v.x + v.y * v.y + v.z * v.z + v.w * v.w;
        }
        for (int off = 32; off; off >>= 1) s += __shfl_down(s, off);
        if (lane == 0) ws[WS_NORM + R] = sqrtf(s);
    }
}

// ============ dp kernel: LCS (0..63) + FSD (64..127), 256 threads ============
__global__ __launch_bounds__(256) void dp_kernel(float* __restrict__ ws) {
    const int t = threadIdx.x;
    if (blockIdx.x < 64) {
        const int b = blockIdx.x;
        __shared__ float S[64 * 68];
        __shared__ float inv[128];
        if (t < 128) {
            float s = 0.f;
            #pragma unroll
            for (int ks = 0; ks < 8; ++ks)
                s += ws[WS_LSQ + (size_t)(b * 8 + ks) * 128 + t];
            inv[t] = 1.0f / sqrtf(s);
        }
        __syncthreads();
        const float* sp = ws + WS_SPART + (size_t)b * 32768;
        #pragma unroll
        for (int qd = 0; qd < 4; ++qd) {
            int idx4 = qd * 256 + t;
            int i = idx4 >> 4, j = (idx4 & 15) * 4;
            float4 v = {0.f, 0.f, 0.f, 0.f};
            #pragma unroll
            for (int ks = 0; ks < 8; ++ks) {
                float4 p = *(const float4*)(sp + (size_t)ks * 4096 + idx4 * 4);
                v.x += p.x; v.y += p.y; v.z += p.z; v.w += p.w;
            }
            float ri = inv[i];
            S[i * 68 + j + 0] = v.x * ri * inv[64 + j + 0];
            S[i * 68 + j + 1] = v.y * ri * inv[64 + j + 1];
            S[i * 68 + j + 2] = v.z * ri * inv[64 + j + 2];
            S[i * 68 + j + 3] = v.w * ri * inv[64 + j + 3];
        }
        __syncthreads();
        if (t < 64) {
            float prev = 0.f, prevprev = 0.f;
            float sval_next = S[t * 68 + 0];
            for (int d = 2; d <= 128; ++d) {
                float s = sval_next;
                int jn = d - t - 1;
                if (jn >= 0 && jn < 64) sval_next = S[t * 68 + jn];
                float up = __shfl_up(prev, 1);
                float dg = __shfl_up(prevprev, 1);
                if (t == 0) { up = 0.f; dg = 0.f; }
                int j = d - t - 1;
                float left = prev;
                float val = (s > 0.5f) ? (dg + s) : fmaxf(up, left);
                float cur = (j >= 1 && j <= 64) ? val : 0.f;
                prevprev = prev;
                prev = cur;
            }
            if (t == 63) ws[WS_LCS + b] = prev;
        }
    } else {
        const int b = blockIdx.x - 64;
        __shared__ float M[32 * 36], G[32 * 36];
        __shared__ float inv[128];
        if (t < 128) {
            int half = t >> 6, sub = t & 63;
            float s = 0.f;
            #pragma unroll
            for (int ks = 0; ks < 4; ++ks)
                s += ws[WS_FSQ + (size_t)((b * 2 + half) * 4 + ks) * 64 + sub];
            inv[t] = 1.0f / sqrtf(s);
        }
        __syncthreads();
        {
            int idx4 = t;
            int i = idx4 >> 3, j = (idx4 & 7) * 4;
            float4 vM = {0.f, 0.f, 0.f, 0.f}, vG = {0.f, 0.f, 0.f, 0.f};
            #pragma unroll
            for (int ks = 0; ks < 4; ++ks) {
                float4 pM = *(const float4*)(ws + WS_MG + (size_t)((b * 2 + 0) * 4 + ks) * 1024 + idx4 * 4);
                float4 pG = *(const float4*)(ws + WS_MG + (size_t)((b * 2 + 1) * 4 + ks) * 1024 + idx4 * 4);
                vM.x += pM.x; vM.y += pM.y; vM.z += pM.z; vM.w += pM.w;
                vG.x += pG.x; vG.y += pG.y; vG.z += pG.z; vG.w += pG.w;
            }
            float riM = inv[i], riG = inv[64 + i];
            M[i * 36 + j + 0] = vM.x * riM * inv[32 + j + 0];
            M[i * 36 + j + 1] = vM.y * riM * inv[32 + j + 1];
            M[i * 36 + j + 2] = vM.z * riM * inv[32 + j + 2];
            M[i * 36 + j + 3] = vM.w * riM * inv[32 + j + 3];
            G[i * 36 + j + 0] = vG.x * riG * inv[96 + j + 0];
            G[i * 36 + j + 1] = vG.y * riG * inv[96 + j + 1];
            G[i * 36 + j + 2] = vG.z * riG * inv[96 + j + 2];
            G[i * 36 + j + 3] = vG.w * riG * inv[96 + j + 3];
        }
        __syncthreads();
        if (t < 32) {
            float prev = 0.f, prevprev = 0.f;
            float m_next = M[t * 36 + 0], g_next = G[t * 36 + 0];
            for (int d = 2; d <= 64; ++d) {
                float m = m_next, g = g_next;
                int jn = d - t - 1;
                if (jn >= 0 && jn < 32) { m_next = M[t * 36 + jn]; g_next = G[t * 36 + jn]; }
                float up = __shfl_up(prev, 1);
                float dg = __shfl_up(prevprev, 1);
                if (t == 0) { up = 0.f; dg = 0.f; }
                int j = d - t - 1;
                float left = prev;
                float x0 = dg * 10.0f;
                float x1 = (g + up) * 10.0f;
                float x2 = (g + left) * 10.0f;
                float mx = fmaxf(x0, fmaxf(x1, x2));
                float lse = mx + __logf(__expf(x0 - mx) + __expf(x1 - mx) + __expf(x2 - mx));
                float val = m + 0.1f * lse;
                float cur = (j >= 1 && j <= 32) ? val : 0.f;
                prevprev = prev;
                prev = cur;
            }
            if (t == 31) ws[WS_FSD + b] = prev;
        }
    }
}

// ============ final combine ============
__device__ float block_reduce(float v, float* red, int t) {
    red[t] = v;
    __syncthreads();
    for (int o = 128; o; o >>= 1) {
        if (t < o) red[t] += red[t + o];
        __syncthreads();
    }
    float r = red[0];
    __syncthreads();
    return r;
}

__global__ __launch_bounds__(256) void final_kernel(
    const float* __restrict__ ai0, const float* __restrict__ ac0,
    const float* __restrict__ ab0, const float* __restrict__ vid0,
    const float* __restrict__ ai1, const float* __restrict__ ac1,
    const float* __restrict__ ab1, const float* __restrict__ vid1,
    const float* __restrict__ ws, float* __restrict__ out) {
    __shared__ float rs0[Bn], rs1[Bn], plsh[Bn];
    __shared__ float red[256];
    int t = threadIdx.x;
    if (t < Bn) {
        float s0 = 0.f, s1 = 0.f, pp = 0.f;
        for (int c = 0; c < NCLS; ++c) {
            float a = vid0[t * NCLS + c], bl = vid1[t * NCLS + c];
            s0 += a; s1 += bl; pp += a * bl;
        }
        rs0[t] = s0;
        rs1[t] = s1;
        plsh[t] = (pp > 0.f) ? 1.f : 0.f;
    }
    __syncthreads();

    float inst0 = 0.f, cont0 = 0.f, back0 = 0.f;
    float inst1 = 0.f, cont1 = 0.f, back1 = 0.f;
    for (int idx = t; idx < Bn * (NCLS + 1); idx += 256) {
        int b = idx / (NCLS + 1), c = idx % (NCLS + 1);
        float v0 = (c < NCLS) ? vid0[b * NCLS + c] : 0.f;
        float v1 = (c < NCLS) ? vid1[b * NCLS + c] : 0.f;
        float wI0 = (c < NCLS) ? (v0 / rs0[b]) : 0.f;
        float wC0 = ((c < NCLS) ? v0 : 1.f) / (rs0[b] + 1.f);
        float wI1 = (c < NCLS) ? (v1 / rs1[b]) : 0.f;
        float wC1 = ((c < NCLS) ? v1 : 1.f) / (rs1[b] + 1.f);
        inst0 += logf(ai0[idx] + 1e-10f) * wI0;
        cont0 += logf(ac0[idx] + 1e-10f) * wC0;
        inst1 += logf(ai1[idx] + 1e-10f) * wI1;
        cont1 += logf(ac1[idx] + 1e-10f) * wC1;
        if (c == NCLS) {
            back0 += logf(ab0[idx] + 1e-10f);
            back1 += logf(ab1[idx] + 1e-10f);
        }
    }
    float sInst0 = block_reduce(inst0, red, t);
    float sCont0 = block_reduce(cont0, red, t);
    float sBack0 = block_reduce(back0, red, t);
    float sInst1 = block_reduce(inst1, red, t);
    float sCont1 = block_reduce(cont1, red, t);
    float sBack1 = block_reduce(back1, red, t);

    float g0 = 0.f, s0v = 0.f, g1 = 0.f, s1v = 0.f;
    for (int i = t; i < 128; i += 256) {
        g0  += ws[WS_GS + i * 4 + 0];
        s0v += ws[WS_GS + i * 4 + 1];
        g1  += ws[WS_GS + i * 4 + 2];
        s1v += ws[WS_GS + i * 4 + 3];
    }
    float sG0 = block_reduce(g0, red, t);
    float sS0 = block_reduce(s0v, red, t);
    float sG1 = block_reduce(g1, red, t);
    float sS1 = block_reduce(s1v, red, t);

    float fv0 = 0.f, fv1 = 0.f;
    if (t < Bn) {
        const float* nm = ws + WS_NORM;
        {
            float ni = nm[0 * Bn + t], nc = nm[1 * Bn + t], nb = nm[2 * Bn + t];
            float f1 = fmaxf(50.0f - ni + nc, 0.f);
            float f2 = fmaxf(50.0f - nc + nb, 0.f);
            float f = f1 + f2 + nb;
            fv0 = f * f;
        }
        {
            float ni = nm[3 * Bn + t], nc = nm[4 * Bn + t], nb = nm[5 * Bn + t];
            float f1 = fmaxf(50.0f - ni + nc, 0.f);
            float f2 = fmaxf(50.0f - nc + nb, 0.f);
            float f = f1 + f2 + nb;
            fv1 = f * f;
        }
    }
    float sFeat0 = block_reduce(fv0, red, t) / (float)Bn;
    float sFeat1 = block_reduce(fv1, red, t) / (float)Bn;

    float posL = 0.f, negL = 0.f, posF = 0.f, negF = 0.f, pln = 0.f;
    if (t < Bn) {
        float pl = plsh[t];
        float lv = ws[WS_LCS + t];
        float fv = ws[WS_FSD + t];
        posL = lv * pl; negL = lv * (1.f - pl);
        posF = fv * pl; negF = fv * (1.f - pl);
        pln = pl;
    }
    float sPosL = block_reduce(posL, red, t);
    float sNegL = block_reduce(negL, red, t);
    float sPosF = block_reduce(posF, red, t);
    float sNegF = block_reduce(negF, red, t);
    float sPln = block_reduce(pln, red, t);

    if (t == 0) {
        float cls0 = -(sInst0 + sCont0 + sBack0) / (float)Bn;
        float cls1 = -(sInst1 + sCont1 + sBack1) / (float)Bn;
        float guide0 = sG0 / (float)Bn;
        float sparse0 = sS0 / (float)(Bn * 2);
        float guide1 = sG1 / (float)Bn;
        float sparse1 = sS1 / (float)(Bn * 2);
        float loss0 = cls0 + 1.0f * guide0 + 5e-05f * sFeat0 + 8e-05f * sparse0;
        float loss1 = cls1 + 1.0f * guide1 + 5e-05f * sFeat1 + 8e-05f * sparse1;
        float acm = 0.5f * (loss0 + loss1);
        float posn = sPln;
        float negn = (float)Bn - posn;
        float lcs_loss = sNegL / (negn + 1e-10f) - sPosL / (posn + 1e-10f);
        float fsd_loss = sNegF / (negn + 1e-10f) - sPosF / (posn + 1e-10f);
        out[0] = acm + 0.01f * lcs_loss + 0.01f * fsd_loss;
    }
}

extern "C" void kernel_launch(void* const* d_in, const int* in_sizes, int n_in,
                              void* d_out, int out_size, void* d_ws, size_t ws_size,
                              hipStream_t stream) {
    (void)in_sizes; (void)n_in; (void)out_size; (void)ws_size;
    const float* ai0  = (const float*)d_in[0];
    const float* ac0  = (const float*)d_in[1];
    const float* ab0  = (const float*)d_in[2];
    const float* vid0 = (const float*)d_in[3];
    const float* att0 = (const float*)d_in[4];
    const float* fi0  = (const float*)d_in[5];
    const float* fc0  = (const float*)d_in[6];
    const float* fb0  = (const float*)d_in[7];
    const float* cas0 = (const float*)d_in[8];
    const float* lcs0 = (const float*)d_in[9];
    const float* fsdA0 = (const float*)d_in[10];
    const float* ai1  = (const float*)d_in[12];
    const float* ac1  = (const float*)d_in[13];
    const float* ab1  = (const float*)d_in[14];
    const float* vid1 = (const float*)d_in[15];
    const float* att1 = (const float*)d_in[16];
    const float* fi1  = (const float*)d_in[17];
    const float* fc1  = (const float*)d_in[18];
    const float* fb1  = (const float*)d_in[19];
    const float* cas1 = (const float*)d_in[20];
    const float* lcs1 = (const float*)d_in[21];
    const float* fsdA1 = (const float*)d_in[22];
    const float* fsdB1 = (const float*)d_in[23];

    float* ws = (float*)d_ws;

    mega_kernel<<<1248, 256, 0, stream>>>(lcs0, lcs1, fsdA0, fsdA1, fsdB1,
                                          vid0, vid1, cas0, att0, cas1, att1,
                                          fi0, fc0, fb0, fi1, fc1, fb1, ws);
    dp_kernel<<<128, 256, 0, stream>>>(ws);
    final_kernel<<<1, 256, 0, stream>>>(ai0, ac0, ab0, vid0, ai1, ac1, ab1, vid1, ws,
                                        (float*)d_out);
}